// Round 1
// baseline (6082.478 us; speedup 1.0000x reference)
//
#include <hip/hip_runtime.h>
#include <stdint.h>

#define Hh 128
#define Aa 16
#define Tt 4
#define K1 144
#define W1T_LD 168   // pad: stride 336B -> bank advance 20 dw -> 2-way (free)
#define WG_LD  136   // pad: stride 272B -> bank advance 4 dw  -> 2-way (free)

typedef float f32x4 __attribute__((ext_vector_type(4)));
typedef __bf16 bf16x8 __attribute__((ext_vector_type(8)));
typedef unsigned short u16x8 __attribute__((ext_vector_type(8)));
typedef unsigned short u16x4 __attribute__((ext_vector_type(4)));

static __device__ __forceinline__ unsigned short f2bf(float f) {
    unsigned u = __builtin_bit_cast(unsigned, f);
    u += 0x7fffu + ((u >> 16) & 1u);   // RNE
    return (unsigned short)(u >> 16);
}

static __device__ __forceinline__ bf16x8 pack8(const float* __restrict__ x) {
    f32x4 a = *(const f32x4*)x;
    f32x4 b = *(const f32x4*)(x + 4);
    u16x8 t;
    t[0] = f2bf(a[0]); t[1] = f2bf(a[1]); t[2] = f2bf(a[2]); t[3] = f2bf(a[3]);
    t[4] = f2bf(b[0]); t[5] = f2bf(b[1]); t[6] = f2bf(b[2]); t[7] = f2bf(b[3]);
    return __builtin_bit_cast(bf16x8, t);
}

static __device__ __forceinline__ bf16x8 zero_bf8() {
    u16x8 z = {0, 0, 0, 0, 0, 0, 0, 0};
    return __builtin_bit_cast(bf16x8, z);
}

// ---------------- bucketing: meta[0..3]=counts, [4..7]=starts, [8..11]=cursors
__global__ void count_kernel(const int* __restrict__ et, int E, int* __restrict__ meta) {
    __shared__ int c[Tt];
    if (threadIdx.x < Tt) c[threadIdx.x] = 0;
    __syncthreads();
    for (int i = blockIdx.x * blockDim.x + threadIdx.x; i < E; i += gridDim.x * blockDim.x)
        atomicAdd(&c[et[i]], 1);
    __syncthreads();
    if (threadIdx.x < Tt) atomicAdd(&meta[threadIdx.x], c[threadIdx.x]);
}

__global__ void scan_kernel(int* __restrict__ meta) {
    if (threadIdx.x == 0 && blockIdx.x == 0) {
        int s = 0;
        for (int t = 0; t < Tt; t++) { int c = meta[t]; meta[4 + t] = s; meta[8 + t] = s; s += c; }
    }
}

__global__ void fill_kernel(const int* __restrict__ et, int E, int* __restrict__ meta,
                            int* __restrict__ bucket) {
    for (int i = blockIdx.x * blockDim.x + threadIdx.x; i < E; i += gridDim.x * blockDim.x) {
        int pos = atomicAdd(&meta[8 + et[i]], 1);
        bucket[pos] = i;
    }
}

// ---------------- layer 1: Y[p][m] = relu(h_in[p] @ W1[t] + b1[t]),  bf16 out
// operand-swapped: A = W1^T (LDS), B = h_in rows (global gather), C'[m=hid][n=edge]
__global__ __launch_bounds__(512) void l1_kernel(
    const float* __restrict__ h, const int* __restrict__ eidx,
    const float* __restrict__ eattr, const float* __restrict__ W1,
    const float* __restrict__ b1, const int* __restrict__ bucket,
    const int* __restrict__ meta, unsigned short* __restrict__ Yg, int E)
{
    __shared__ unsigned short W1T[128 * W1T_LD];
    __shared__ float b1s[128];
    const int t = blockIdx.x & 3;
    const int lb = blockIdx.x >> 2;
    const int nb = gridDim.x >> 2;
    const int tid = threadIdx.x;

    for (int idx = tid; idx < K1 * Hh; idx += 512) {
        int k = idx >> 7, n = idx & 127;
        W1T[n * W1T_LD + k] = f2bf(W1[((size_t)t * K1 + k) * Hh + n]);
    }
    for (int idx = tid; idx < (W1T_LD - K1) * Hh; idx += 512) {
        int k = K1 + (idx % (W1T_LD - K1)), n = idx / (W1T_LD - K1);
        W1T[n * W1T_LD + k] = 0;   // zero pad k=144..167 (read up to 159)
    }
    if (tid < 128) b1s[tid] = b1[t * Hh + tid];
    __syncthreads();

    const int cnt = meta[t], tstart = meta[4 + t];
    const int tend = tstart + cnt;
    const int ntiles = (cnt + 255) >> 8;
    const int w = tid >> 6, lane = tid & 63;
    const int l15 = lane & 15, q = lane >> 4;

    for (int tile = lb; tile < ntiles; tile += nb) {
        const int p0 = tstart + tile * 256 + w * 32;
        const int pa = p0 + l15, pb = p0 + 16 + l15;
        const bool va = pa < tend, vb = pb < tend;
        const int ea = bucket[va ? pa : tstart];
        const int eb = bucket[vb ? pb : tstart];
        const int sa = eidx[ea], sb = eidx[eb];
        const float* __restrict__ hA = h + (size_t)sa * Hh;
        const float* __restrict__ hB = h + (size_t)sb * Hh;

        f32x4 acc[8][2];
        #pragma unroll
        for (int mt = 0; mt < 8; mt++) {
            acc[mt][0] = (f32x4){0.f, 0.f, 0.f, 0.f};
            acc[mt][1] = (f32x4){0.f, 0.f, 0.f, 0.f};
        }

        #pragma unroll
        for (int ks = 0; ks < 5; ks++) {
            const int k0 = ks * 32;
            bf16x8 fb_a, fb_b;
            if (ks < 4) {
                fb_a = pack8(hA + k0 + q * 8);
                fb_b = pack8(hB + k0 + q * 8);
            } else if (q < 2) {
                fb_a = pack8(eattr + (size_t)ea * Aa + q * 8);
                fb_b = pack8(eattr + (size_t)eb * Aa + q * 8);
            } else {
                fb_a = zero_bf8();
                fb_b = zero_bf8();
            }
            #pragma unroll
            for (int mt = 0; mt < 8; mt++) {
                bf16x8 fa = *(const bf16x8*)&W1T[(mt * 16 + l15) * W1T_LD + k0 + q * 8];
                acc[mt][0] = __builtin_amdgcn_mfma_f32_16x16x32_bf16(fa, fb_a, acc[mt][0], 0, 0, 0);
                acc[mt][1] = __builtin_amdgcn_mfma_f32_16x16x32_bf16(fa, fb_b, acc[mt][1], 0, 0, 0);
            }
        }

        #pragma unroll
        for (int mt = 0; mt < 8; mt++) {
            f32x4 bias = *(const f32x4*)&b1s[mt * 16 + q * 4];
            if (va) {
                u16x4 y;
                #pragma unroll
                for (int i = 0; i < 4; i++) {
                    float v = acc[mt][0][i] + bias[i];
                    y[i] = f2bf(v > 0.f ? v : 0.f);
                }
                *(u16x4*)&Yg[(size_t)pa * Hh + mt * 16 + q * 4] = y;
            }
            if (vb) {
                u16x4 y;
                #pragma unroll
                for (int i = 0; i < 4; i++) {
                    float v = acc[mt][1][i] + bias[i];
                    y[i] = f2bf(v > 0.f ? v : 0.f);
                }
                *(u16x4*)&Yg[(size_t)pb * Hh + mt * 16 + q * 4] = y;
            }
        }
    }
}

// ---------------- layer 2: m = Y @ W2[t] + b2[t], atomically scattered to msg[dst]
__global__ __launch_bounds__(512) void l2_kernel(
    const float* __restrict__ W2, const float* __restrict__ b2,
    const int* __restrict__ eidx, const int* __restrict__ bucket,
    const int* __restrict__ meta, const unsigned short* __restrict__ Yg,
    float* __restrict__ msg, int E)
{
    __shared__ unsigned short W2T[128 * WG_LD];
    __shared__ float b2s[128];
    __shared__ int dstS[256];
    const int t = blockIdx.x & 3;
    const int lb = blockIdx.x >> 2;
    const int nb = gridDim.x >> 2;
    const int tid = threadIdx.x;

    for (int idx = tid; idx < Hh * Hh; idx += 512) {
        int k = idx >> 7, n = idx & 127;
        W2T[n * WG_LD + k] = f2bf(W2[((size_t)t * Hh + k) * Hh + n]);
    }
    if (tid < 128) b2s[tid] = b2[t * Hh + tid];

    const int cnt = meta[t], tstart = meta[4 + t];
    const int tend = tstart + cnt;
    const int ntiles = (cnt + 255) >> 8;
    const int w = tid >> 6, lane = tid & 63;
    const int l15 = lane & 15, q = lane >> 4;

    for (int tile = lb; tile < ntiles; tile += nb) {
        const int base = tstart + tile * 256;
        __syncthreads();   // covers weight staging (1st iter) + dstS reuse (later iters)
        if (tid < 256) {
            int p = base + tid;
            int e = bucket[p < tend ? p : tstart];
            dstS[tid] = eidx[E + e];
        }
        __syncthreads();

        const int p0 = base + w * 32;
        const int pa = p0 + l15, pb = p0 + 16 + l15;
        const bool va = pa < tend, vb = pb < tend;
        const size_t ra = (size_t)(va ? pa : tstart) * Hh;
        const size_t rb = (size_t)(vb ? pb : tstart) * Hh;

        f32x4 acc[8][2];
        #pragma unroll
        for (int mt = 0; mt < 8; mt++) {
            acc[mt][0] = (f32x4){0.f, 0.f, 0.f, 0.f};
            acc[mt][1] = (f32x4){0.f, 0.f, 0.f, 0.f};
        }

        #pragma unroll
        for (int ks = 0; ks < 4; ks++) {
            const int k0 = ks * 32;
            bf16x8 fb_a = *(const bf16x8*)&Yg[ra + k0 + q * 8];
            bf16x8 fb_b = *(const bf16x8*)&Yg[rb + k0 + q * 8];
            #pragma unroll
            for (int mt = 0; mt < 8; mt++) {
                bf16x8 fa = *(const bf16x8*)&W2T[(mt * 16 + l15) * WG_LD + k0 + q * 8];
                acc[mt][0] = __builtin_amdgcn_mfma_f32_16x16x32_bf16(fa, fb_a, acc[mt][0], 0, 0, 0);
                acc[mt][1] = __builtin_amdgcn_mfma_f32_16x16x32_bf16(fa, fb_b, acc[mt][1], 0, 0, 0);
            }
        }

        #pragma unroll
        for (int mt = 0; mt < 8; mt++) {
            f32x4 bias = *(const f32x4*)&b2s[mt * 16 + q * 4];
            if (va) {
                int dst = dstS[w * 32 + l15];
                float* mp = msg + (size_t)dst * Hh + mt * 16 + q * 4;
                #pragma unroll
                for (int i = 0; i < 4; i++) atomicAdd(mp + i, acc[mt][0][i] + bias[i]);
            }
            if (vb) {
                int dst = dstS[w * 32 + 16 + l15];
                float* mp = msg + (size_t)dst * Hh + mt * 16 + q * 4;
                #pragma unroll
                for (int i = 0; i < 4; i++) atomicAdd(mp + i, acc[mt][1][i] + bias[i]);
            }
        }
    }
}

// ---------------- GRU: out = (1-z)*n + z*h, gate-by-gate LDS weight staging
__global__ __launch_bounds__(512) void gru_kernel(
    const float* __restrict__ h, const float* __restrict__ msg,
    const float* __restrict__ w_ih, const float* __restrict__ w_hh,
    const float* __restrict__ b_ih, const float* __restrict__ b_hh,
    float* __restrict__ out, int N)
{
    __shared__ unsigned short Wg[128 * WG_LD];
    const int tid = threadIdx.x;
    const int w = tid >> 6, lane = tid & 63;
    const int l15 = lane & 15, q = lane >> 4;
    const int nodebase = blockIdx.x * 128 + w * 16;
    const int nA = min(nodebase + l15, N - 1);
    const float* __restrict__ mrow = msg + (size_t)nA * Hh;
    const float* __restrict__ hrow = h + (size_t)nA * Hh;

    f32x4 gr[8], gz[8], gin[8], ghn[8];
    #pragma unroll
    for (int ct = 0; ct < 8; ct++) {
        gr[ct] = (f32x4){0.f, 0.f, 0.f, 0.f};
        gz[ct] = (f32x4){0.f, 0.f, 0.f, 0.f};
        gin[ct] = (f32x4){0.f, 0.f, 0.f, 0.f};
        ghn[ct] = (f32x4){0.f, 0.f, 0.f, 0.f};
    }

    auto stage = [&](const float* __restrict__ Ws, int gate) {
        __syncthreads();
        for (int idx = tid; idx < Hh * Hh; idx += 512) {
            int o = idx >> 7, k = idx & 127;
            Wg[o * WG_LD + k] = f2bf(Ws[((size_t)gate * Hh + o) * Hh + k]);
        }
        __syncthreads();
    };
    auto matmul = [&](const float* __restrict__ arow, f32x4* acc) {
        #pragma unroll
        for (int ks = 0; ks < 4; ks++) {
            bf16x8 fa = pack8(arow + ks * 32 + q * 8);
            #pragma unroll
            for (int ct = 0; ct < 8; ct++) {
                bf16x8 fb = *(const bf16x8*)&Wg[(ct * 16 + l15) * WG_LD + ks * 32 + q * 8];
                acc[ct] = __builtin_amdgcn_mfma_f32_16x16x32_bf16(fa, fb, acc[ct], 0, 0, 0);
            }
        }
    };

    stage(w_ih, 0); matmul(mrow, gr);
    stage(w_hh, 0); matmul(hrow, gr);
    stage(w_ih, 1); matmul(mrow, gz);
    stage(w_hh, 1); matmul(hrow, gz);
    stage(w_ih, 2); matmul(mrow, gin);
    stage(w_hh, 2); matmul(hrow, ghn);

    #pragma unroll
    for (int ct = 0; ct < 8; ct++) {
        int c = ct * 16 + l15;
        float bir = b_ih[c],       bhr = b_hh[c];
        float biz = b_ih[128 + c], bhz = b_hh[128 + c];
        float bin = b_ih[256 + c], bhn = b_hh[256 + c];
        #pragma unroll
        for (int i = 0; i < 4; i++) {
            int node = nodebase + q * 4 + i;
            if (node < N) {
                float rv = 1.f / (1.f + __expf(-(gr[ct][i] + bir + bhr)));
                float zv = 1.f / (1.f + __expf(-(gz[ct][i] + biz + bhz)));
                float npre = gin[ct][i] + bin + rv * (ghn[ct][i] + bhn);
                float e2 = __expf(-2.f * npre);
                float nv = (1.f - e2) / (1.f + e2);
                float hv = h[(size_t)node * Hh + c];
                out[(size_t)node * Hh + c] = (1.f - zv) * nv + zv * hv;
            }
        }
    }
}

extern "C" void kernel_launch(void* const* d_in, const int* in_sizes, int n_in,
                              void* d_out, int out_size, void* d_ws, size_t ws_size,
                              hipStream_t stream)
{
    const float* h     = (const float*)d_in[0];
    const int*   eidx  = (const int*)d_in[1];
    const int*   et    = (const int*)d_in[2];
    const float* eattr = (const float*)d_in[3];
    const float* W1    = (const float*)d_in[4];
    const float* b1    = (const float*)d_in[5];
    const float* W2    = (const float*)d_in[6];
    const float* b2    = (const float*)d_in[7];
    const float* w_ih  = (const float*)d_in[8];
    const float* w_hh  = (const float*)d_in[9];
    const float* b_ih  = (const float*)d_in[10];
    const float* b_hh  = (const float*)d_in[11];

    const int N = in_sizes[0] / Hh;
    const int E = in_sizes[1] / 2;

    char* ws = (char*)d_ws;
    float* msg = (float*)ws;                                  // N*H f32 = 25.6 MB
    size_t off = (size_t)N * Hh * sizeof(float);
    unsigned short* Yg = (unsigned short*)(ws + off);         // E*H bf16 = 204.8 MB
    off += (size_t)E * Hh * sizeof(unsigned short);
    int* bucket = (int*)(ws + off);                           // E int = 3.2 MB
    off += (size_t)E * sizeof(int);
    int* meta = (int*)(ws + off);                             // 12 ints

    hipMemsetAsync(msg, 0, (size_t)N * Hh * sizeof(float), stream);
    hipMemsetAsync(meta, 0, 12 * sizeof(int), stream);

    count_kernel<<<512, 256, 0, stream>>>(et, E, meta);
    scan_kernel<<<1, 64, 0, stream>>>(meta);
    fill_kernel<<<512, 256, 0, stream>>>(et, E, meta, bucket);

    l1_kernel<<<1024, 512, 0, stream>>>(h, eidx, eattr, W1, b1, bucket, meta, Yg, E);
    l2_kernel<<<1024, 512, 0, stream>>>(W2, b2, eidx, bucket, meta, Yg, msg, E);

    int gblocks = (N + 127) / 128;
    gru_kernel<<<gblocks, 512, 0, stream>>>(h, msg, w_ih, w_hh, b_ih, b_hh, (float*)d_out, N);
}

// Round 2
// 1807.974 us; speedup vs baseline: 3.3643x; 3.3643x over previous
//
#include <hip/hip_runtime.h>
#include <stdint.h>

#define Hh 128
#define Aa 16
#define Tt 4
#define K1 144
#define W1T_LD 168   // pad: stride 336B -> bank advance 20 dw -> 2-way (free)
#define WG_LD  136   // pad: stride 272B -> bank advance 4 dw  -> 2-way (free)

typedef float f32x4 __attribute__((ext_vector_type(4)));
typedef __bf16 bf16x8 __attribute__((ext_vector_type(8)));
typedef unsigned short u16x8 __attribute__((ext_vector_type(8)));
typedef unsigned short u16x4 __attribute__((ext_vector_type(4)));

static __device__ __forceinline__ unsigned short f2bf(float f) {
    unsigned u = __builtin_bit_cast(unsigned, f);
    u += 0x7fffu + ((u >> 16) & 1u);   // RNE
    return (unsigned short)(u >> 16);
}

static __device__ __forceinline__ bf16x8 pack8(const float* __restrict__ x) {
    f32x4 a = *(const f32x4*)x;
    f32x4 b = *(const f32x4*)(x + 4);
    u16x8 t;
    t[0] = f2bf(a[0]); t[1] = f2bf(a[1]); t[2] = f2bf(a[2]); t[3] = f2bf(a[3]);
    t[4] = f2bf(b[0]); t[5] = f2bf(b[1]); t[6] = f2bf(b[2]); t[7] = f2bf(b[3]);
    return __builtin_bit_cast(bf16x8, t);
}

static __device__ __forceinline__ bf16x8 zero_bf8() {
    u16x8 z = {0, 0, 0, 0, 0, 0, 0, 0};
    return __builtin_bit_cast(bf16x8, z);
}

// ---------------- bucketing: meta[0..3]=counts, [4..7]=starts, [8..11]=cursors
// Ballot-based: 4 LDS atomics per wave, 4 global atomics per block (was: 1 global
// atomic per EDGE -> 200K serialized RMWs per address -> 4.3 ms. Guideline 12.)
__global__ void count_kernel(const int* __restrict__ et, int E, int* __restrict__ meta) {
    __shared__ int c[Tt];
    const int tid = threadIdx.x;
    const int lane = tid & 63;
    if (tid < Tt) c[tid] = 0;
    __syncthreads();
    for (int i = blockIdx.x * blockDim.x + tid; i < E; i += gridDim.x * blockDim.x) {
        int te = et[i];
        #pragma unroll
        for (int t = 0; t < Tt; t++) {
            unsigned long long m = __ballot(te == t);
            if (lane == t) atomicAdd(&c[t], __popcll(m));
        }
    }
    __syncthreads();
    if (tid < Tt) atomicAdd(&meta[tid], c[tid]);
}

__global__ void scan_kernel(int* __restrict__ meta) {
    if (threadIdx.x == 0 && blockIdx.x == 0) {
        int s = 0;
        for (int t = 0; t < Tt; t++) { int c = meta[t]; meta[4 + t] = s; meta[8 + t] = s; s += c; }
    }
}

// Two-pass per block: (1) block histogram via wave ballots, (2) reserve a global
// range (4 atomics/block), then lanes place edges at base + wave-claim + mbcnt.
__global__ void fill_kernel(const int* __restrict__ et, int E, int* __restrict__ meta,
                            int* __restrict__ bucket) {
    __shared__ int hist[Tt];
    __shared__ int cur[Tt];
    const int tid = threadIdx.x;
    const int lane = tid & 63;
    const int stride = gridDim.x * blockDim.x;
    const int i0 = blockIdx.x * blockDim.x + tid;

    if (tid < Tt) hist[tid] = 0;
    __syncthreads();

    // pass 1: block histogram
    for (int i = i0; i < E; i += stride) {
        int te = et[i];
        #pragma unroll
        for (int t = 0; t < Tt; t++) {
            unsigned long long m = __ballot(te == t);
            if (lane == t) atomicAdd(&hist[t], __popcll(m));
        }
    }
    __syncthreads();
    if (tid < Tt) cur[tid] = atomicAdd(&meta[8 + tid], hist[tid]);
    __syncthreads();

    // pass 2: place
    for (int i = i0; i < E; i += stride) {
        int te = et[i];
        unsigned long long m[Tt];
        #pragma unroll
        for (int t = 0; t < Tt; t++) m[t] = __ballot(te == t);
        int wbase = 0;
        if (lane < Tt) wbase = atomicAdd(&cur[lane], __popcll(m[lane]));
        int mybase = __shfl(wbase, te);
        int off = __popcll(m[te] & ((1ull << lane) - 1ull));
        bucket[mybase + off] = i;
    }
}

// ---------------- layer 1: Y[p][m] = relu(h_in[p] @ W1[t] + b1[t]),  bf16 out
// operand-swapped: A = W1^T (LDS), B = h_in rows (global gather), C'[m=hid][n=edge]
__global__ __launch_bounds__(512) void l1_kernel(
    const float* __restrict__ h, const int* __restrict__ eidx,
    const float* __restrict__ eattr, const float* __restrict__ W1,
    const float* __restrict__ b1, const int* __restrict__ bucket,
    const int* __restrict__ meta, unsigned short* __restrict__ Yg, int E)
{
    __shared__ unsigned short W1T[128 * W1T_LD];
    __shared__ float b1s[128];
    const int t = blockIdx.x & 3;
    const int lb = blockIdx.x >> 2;
    const int nb = gridDim.x >> 2;
    const int tid = threadIdx.x;

    for (int idx = tid; idx < K1 * Hh; idx += 512) {
        int k = idx >> 7, n = idx & 127;
        W1T[n * W1T_LD + k] = f2bf(W1[((size_t)t * K1 + k) * Hh + n]);
    }
    for (int idx = tid; idx < (W1T_LD - K1) * Hh; idx += 512) {
        int k = K1 + (idx % (W1T_LD - K1)), n = idx / (W1T_LD - K1);
        W1T[n * W1T_LD + k] = 0;   // zero pad k=144..167 (read up to 159)
    }
    if (tid < 128) b1s[tid] = b1[t * Hh + tid];
    __syncthreads();

    const int cnt = meta[t], tstart = meta[4 + t];
    const int tend = tstart + cnt;
    const int ntiles = (cnt + 255) >> 8;
    const int w = tid >> 6, lane = tid & 63;
    const int l15 = lane & 15, q = lane >> 4;

    for (int tile = lb; tile < ntiles; tile += nb) {
        const int p0 = tstart + tile * 256 + w * 32;
        const int pa = p0 + l15, pb = p0 + 16 + l15;
        const bool va = pa < tend, vb = pb < tend;
        const int ea = bucket[va ? pa : tstart];
        const int eb = bucket[vb ? pb : tstart];
        const int sa = eidx[ea], sb = eidx[eb];
        const float* __restrict__ hA = h + (size_t)sa * Hh;
        const float* __restrict__ hB = h + (size_t)sb * Hh;

        f32x4 acc[8][2];
        #pragma unroll
        for (int mt = 0; mt < 8; mt++) {
            acc[mt][0] = (f32x4){0.f, 0.f, 0.f, 0.f};
            acc[mt][1] = (f32x4){0.f, 0.f, 0.f, 0.f};
        }

        #pragma unroll
        for (int ks = 0; ks < 5; ks++) {
            const int k0 = ks * 32;
            bf16x8 fb_a, fb_b;
            if (ks < 4) {
                fb_a = pack8(hA + k0 + q * 8);
                fb_b = pack8(hB + k0 + q * 8);
            } else if (q < 2) {
                fb_a = pack8(eattr + (size_t)ea * Aa + q * 8);
                fb_b = pack8(eattr + (size_t)eb * Aa + q * 8);
            } else {
                fb_a = zero_bf8();
                fb_b = zero_bf8();
            }
            #pragma unroll
            for (int mt = 0; mt < 8; mt++) {
                bf16x8 fa = *(const bf16x8*)&W1T[(mt * 16 + l15) * W1T_LD + k0 + q * 8];
                acc[mt][0] = __builtin_amdgcn_mfma_f32_16x16x32_bf16(fa, fb_a, acc[mt][0], 0, 0, 0);
                acc[mt][1] = __builtin_amdgcn_mfma_f32_16x16x32_bf16(fa, fb_b, acc[mt][1], 0, 0, 0);
            }
        }

        #pragma unroll
        for (int mt = 0; mt < 8; mt++) {
            f32x4 bias = *(const f32x4*)&b1s[mt * 16 + q * 4];
            if (va) {
                u16x4 y;
                #pragma unroll
                for (int i = 0; i < 4; i++) {
                    float v = acc[mt][0][i] + bias[i];
                    y[i] = f2bf(v > 0.f ? v : 0.f);
                }
                *(u16x4*)&Yg[(size_t)pa * Hh + mt * 16 + q * 4] = y;
            }
            if (vb) {
                u16x4 y;
                #pragma unroll
                for (int i = 0; i < 4; i++) {
                    float v = acc[mt][1][i] + bias[i];
                    y[i] = f2bf(v > 0.f ? v : 0.f);
                }
                *(u16x4*)&Yg[(size_t)pb * Hh + mt * 16 + q * 4] = y;
            }
        }
    }
}

// ---------------- layer 2: m = Y @ W2[t] + b2[t], atomically scattered to msg[dst]
__global__ __launch_bounds__(512) void l2_kernel(
    const float* __restrict__ W2, const float* __restrict__ b2,
    const int* __restrict__ eidx, const int* __restrict__ bucket,
    const int* __restrict__ meta, const unsigned short* __restrict__ Yg,
    float* __restrict__ msg, int E)
{
    __shared__ unsigned short W2T[128 * WG_LD];
    __shared__ float b2s[128];
    __shared__ int dstS[256];
    const int t = blockIdx.x & 3;
    const int lb = blockIdx.x >> 2;
    const int nb = gridDim.x >> 2;
    const int tid = threadIdx.x;

    for (int idx = tid; idx < Hh * Hh; idx += 512) {
        int k = idx >> 7, n = idx & 127;
        W2T[n * WG_LD + k] = f2bf(W2[((size_t)t * Hh + k) * Hh + n]);
    }
    if (tid < 128) b2s[tid] = b2[t * Hh + tid];

    const int cnt = meta[t], tstart = meta[4 + t];
    const int tend = tstart + cnt;
    const int ntiles = (cnt + 255) >> 8;
    const int w = tid >> 6, lane = tid & 63;
    const int l15 = lane & 15, q = lane >> 4;

    for (int tile = lb; tile < ntiles; tile += nb) {
        const int base = tstart + tile * 256;
        __syncthreads();   // covers weight staging (1st iter) + dstS reuse (later iters)
        if (tid < 256) {
            int p = base + tid;
            int e = bucket[p < tend ? p : tstart];
            dstS[tid] = eidx[E + e];
        }
        __syncthreads();

        const int p0 = base + w * 32;
        const int pa = p0 + l15, pb = p0 + 16 + l15;
        const bool va = pa < tend, vb = pb < tend;
        const size_t ra = (size_t)(va ? pa : tstart) * Hh;
        const size_t rb = (size_t)(vb ? pb : tstart) * Hh;

        f32x4 acc[8][2];
        #pragma unroll
        for (int mt = 0; mt < 8; mt++) {
            acc[mt][0] = (f32x4){0.f, 0.f, 0.f, 0.f};
            acc[mt][1] = (f32x4){0.f, 0.f, 0.f, 0.f};
        }

        #pragma unroll
        for (int ks = 0; ks < 4; ks++) {
            const int k0 = ks * 32;
            bf16x8 fb_a = *(const bf16x8*)&Yg[ra + k0 + q * 8];
            bf16x8 fb_b = *(const bf16x8*)&Yg[rb + k0 + q * 8];
            #pragma unroll
            for (int mt = 0; mt < 8; mt++) {
                bf16x8 fa = *(const bf16x8*)&W2T[(mt * 16 + l15) * WG_LD + k0 + q * 8];
                acc[mt][0] = __builtin_amdgcn_mfma_f32_16x16x32_bf16(fa, fb_a, acc[mt][0], 0, 0, 0);
                acc[mt][1] = __builtin_amdgcn_mfma_f32_16x16x32_bf16(fa, fb_b, acc[mt][1], 0, 0, 0);
            }
        }

        #pragma unroll
        for (int mt = 0; mt < 8; mt++) {
            f32x4 bias = *(const f32x4*)&b2s[mt * 16 + q * 4];
            if (va) {
                int dst = dstS[w * 32 + l15];
                float* mp = msg + (size_t)dst * Hh + mt * 16 + q * 4;
                #pragma unroll
                for (int i = 0; i < 4; i++) atomicAdd(mp + i, acc[mt][0][i] + bias[i]);
            }
            if (vb) {
                int dst = dstS[w * 32 + 16 + l15];
                float* mp = msg + (size_t)dst * Hh + mt * 16 + q * 4;
                #pragma unroll
                for (int i = 0; i < 4; i++) atomicAdd(mp + i, acc[mt][1][i] + bias[i]);
            }
        }
    }
}

// ---------------- GRU: out = (1-z)*n + z*h, gate-by-gate LDS weight staging
__global__ __launch_bounds__(512) void gru_kernel(
    const float* __restrict__ h, const float* __restrict__ msg,
    const float* __restrict__ w_ih, const float* __restrict__ w_hh,
    const float* __restrict__ b_ih, const float* __restrict__ b_hh,
    float* __restrict__ out, int N)
{
    __shared__ unsigned short Wg[128 * WG_LD];
    const int tid = threadIdx.x;
    const int w = tid >> 6, lane = tid & 63;
    const int l15 = lane & 15, q = lane >> 4;
    const int nodebase = blockIdx.x * 128 + w * 16;
    const int nA = min(nodebase + l15, N - 1);
    const float* __restrict__ mrow = msg + (size_t)nA * Hh;
    const float* __restrict__ hrow = h + (size_t)nA * Hh;

    f32x4 gr[8], gz[8], gin[8], ghn[8];
    #pragma unroll
    for (int ct = 0; ct < 8; ct++) {
        gr[ct] = (f32x4){0.f, 0.f, 0.f, 0.f};
        gz[ct] = (f32x4){0.f, 0.f, 0.f, 0.f};
        gin[ct] = (f32x4){0.f, 0.f, 0.f, 0.f};
        ghn[ct] = (f32x4){0.f, 0.f, 0.f, 0.f};
    }

    auto stage = [&](const float* __restrict__ Ws, int gate) {
        __syncthreads();
        for (int idx = tid; idx < Hh * Hh; idx += 512) {
            int o = idx >> 7, k = idx & 127;
            Wg[o * WG_LD + k] = f2bf(Ws[((size_t)gate * Hh + o) * Hh + k]);
        }
        __syncthreads();
    };
    auto matmul = [&](const float* __restrict__ arow, f32x4* acc) {
        #pragma unroll
        for (int ks = 0; ks < 4; ks++) {
            bf16x8 fa = pack8(arow + ks * 32 + q * 8);
            #pragma unroll
            for (int ct = 0; ct < 8; ct++) {
                bf16x8 fb = *(const bf16x8*)&Wg[(ct * 16 + l15) * WG_LD + ks * 32 + q * 8];
                acc[ct] = __builtin_amdgcn_mfma_f32_16x16x32_bf16(fa, fb, acc[ct], 0, 0, 0);
            }
        }
    };

    stage(w_ih, 0); matmul(mrow, gr);
    stage(w_hh, 0); matmul(hrow, gr);
    stage(w_ih, 1); matmul(mrow, gz);
    stage(w_hh, 1); matmul(hrow, gz);
    stage(w_ih, 2); matmul(mrow, gin);
    stage(w_hh, 2); matmul(hrow, ghn);

    #pragma unroll
    for (int ct = 0; ct < 8; ct++) {
        int c = ct * 16 + l15;
        float bir = b_ih[c],       bhr = b_hh[c];
        float biz = b_ih[128 + c], bhz = b_hh[128 + c];
        float bin = b_ih[256 + c], bhn = b_hh[256 + c];
        #pragma unroll
        for (int i = 0; i < 4; i++) {
            int node = nodebase + q * 4 + i;
            if (node < N) {
                float rv = 1.f / (1.f + __expf(-(gr[ct][i] + bir + bhr)));
                float zv = 1.f / (1.f + __expf(-(gz[ct][i] + biz + bhz)));
                float npre = gin[ct][i] + bin + rv * (ghn[ct][i] + bhn);
                float e2 = __expf(-2.f * npre);
                float nv = (1.f - e2) / (1.f + e2);
                float hv = h[(size_t)node * Hh + c];
                out[(size_t)node * Hh + c] = (1.f - zv) * nv + zv * hv;
            }
        }
    }
}

extern "C" void kernel_launch(void* const* d_in, const int* in_sizes, int n_in,
                              void* d_out, int out_size, void* d_ws, size_t ws_size,
                              hipStream_t stream)
{
    const float* h     = (const float*)d_in[0];
    const int*   eidx  = (const int*)d_in[1];
    const int*   et    = (const int*)d_in[2];
    const float* eattr = (const float*)d_in[3];
    const float* W1    = (const float*)d_in[4];
    const float* b1    = (const float*)d_in[5];
    const float* W2    = (const float*)d_in[6];
    const float* b2    = (const float*)d_in[7];
    const float* w_ih  = (const float*)d_in[8];
    const float* w_hh  = (const float*)d_in[9];
    const float* b_ih  = (const float*)d_in[10];
    const float* b_hh  = (const float*)d_in[11];

    const int N = in_sizes[0] / Hh;
    const int E = in_sizes[1] / 2;

    char* ws = (char*)d_ws;
    float* msg = (float*)ws;                                  // N*H f32 = 25.6 MB
    size_t off = (size_t)N * Hh * sizeof(float);
    unsigned short* Yg = (unsigned short*)(ws + off);         // E*H bf16 = 204.8 MB
    off += (size_t)E * Hh * sizeof(unsigned short);
    int* bucket = (int*)(ws + off);                           // E int = 3.2 MB
    off += (size_t)E * sizeof(int);
    int* meta = (int*)(ws + off);                             // 12 ints

    hipMemsetAsync(msg, 0, (size_t)N * Hh * sizeof(float), stream);
    hipMemsetAsync(meta, 0, 12 * sizeof(int), stream);

    count_kernel<<<512, 256, 0, stream>>>(et, E, meta);
    scan_kernel<<<1, 64, 0, stream>>>(meta);
    fill_kernel<<<512, 256, 0, stream>>>(et, E, meta, bucket);

    l1_kernel<<<1024, 512, 0, stream>>>(h, eidx, eattr, W1, b1, bucket, meta, Yg, E);
    l2_kernel<<<1024, 512, 0, stream>>>(W2, b2, eidx, bucket, meta, Yg, msg, E);

    int gblocks = (N + 127) / 128;
    gru_kernel<<<gblocks, 512, 0, stream>>>(h, msg, w_ih, w_hh, b_ih, b_hh, (float*)d_out, N);
}

// Round 3
// 640.248 us; speedup vs baseline: 9.5002x; 2.8239x over previous
//
#include <hip/hip_runtime.h>
#include <stdint.h>

#define Hh 128
#define Aa 16
#define Tt 4
#define K1 144
#define W1T_LD 168   // pad: stride 336B -> bank advance 20 dw -> 2-way (free)
#define WG_LD  136   // pad: stride 272B -> bank advance 4 dw  -> 2-way (free)

typedef float f32x4 __attribute__((ext_vector_type(4)));
typedef __bf16 bf16x8 __attribute__((ext_vector_type(8)));
typedef unsigned short u16x8 __attribute__((ext_vector_type(8)));
typedef unsigned short u16x4 __attribute__((ext_vector_type(4)));

static __device__ __forceinline__ unsigned short f2bf(float f) {
    unsigned u = __builtin_bit_cast(unsigned, f);
    u += 0x7fffu + ((u >> 16) & 1u);   // RNE
    return (unsigned short)(u >> 16);
}

static __device__ __forceinline__ float bf2f(unsigned short u) {
    return __builtin_bit_cast(float, (unsigned)u << 16);
}

static __device__ __forceinline__ bf16x8 pack8(const float* __restrict__ x) {
    f32x4 a = *(const f32x4*)x;
    f32x4 b = *(const f32x4*)(x + 4);
    u16x8 t;
    t[0] = f2bf(a[0]); t[1] = f2bf(a[1]); t[2] = f2bf(a[2]); t[3] = f2bf(a[3]);
    t[4] = f2bf(b[0]); t[5] = f2bf(b[1]); t[6] = f2bf(b[2]); t[7] = f2bf(b[3]);
    return __builtin_bit_cast(bf16x8, t);
}

static __device__ __forceinline__ bf16x8 zero_bf8() {
    u16x8 z = {0, 0, 0, 0, 0, 0, 0, 0};
    return __builtin_bit_cast(bf16x8, z);
}

// ============ bucketing by (type, dst): 4N bins, exclusive scan -> rowptr2 ============
__global__ void hist_kernel(const int* __restrict__ et, const int* __restrict__ eidx,
                            int E, int N, int* __restrict__ deg2) {
    for (int i = blockIdx.x * blockDim.x + threadIdx.x; i < E; i += gridDim.x * blockDim.x)
        atomicAdd(&deg2[et[i] * N + eidx[E + i]], 1);   // ~4 colliders/bin avg
}

// per-1024-chunk block sums
__global__ void scanA_kernel(const int* __restrict__ deg2, int nb, int* __restrict__ bsum) {
    __shared__ int red[256];
    const int t = threadIdx.x;
    const int i0 = blockIdx.x * 1024 + t * 4;
    int s = 0;
    #pragma unroll
    for (int j = 0; j < 4; j++) if (i0 + j < nb) s += deg2[i0 + j];
    red[t] = s; __syncthreads();
    for (int d = 128; d > 0; d >>= 1) {
        if (t < d) red[t] += red[t + d];
        __syncthreads();
    }
    if (t == 0) bsum[blockIdx.x] = red[0];
}

// single-block exclusive scan of block sums (nblocks <= 256)
__global__ void scanB_kernel(int* __restrict__ bsum, int nblocks,
                             int* __restrict__ rowptr2, int nb) {
    __shared__ int ts[256];
    const int t = threadIdx.x;
    int v = (t < nblocks) ? bsum[t] : 0;
    ts[t] = v; __syncthreads();
    for (int d = 1; d < 256; d <<= 1) {
        int x = (t >= d) ? ts[t - d] : 0;
        __syncthreads();
        ts[t] += x;
        __syncthreads();
    }
    if (t < nblocks) bsum[t] = ts[t] - v;   // exclusive
    if (t == 255) rowptr2[nb] = ts[255];    // total == E
}

// per-chunk exclusive scan + global offset; writes rowptr2 and cursor copy
__global__ void scanC_kernel(const int* __restrict__ deg2, int nb,
                             const int* __restrict__ bsum,
                             int* __restrict__ rowptr2, int* __restrict__ cursor2) {
    __shared__ int ts[256];
    const int t = threadIdx.x;
    const int i0 = blockIdx.x * 1024 + t * 4;
    int v[4];
    #pragma unroll
    for (int j = 0; j < 4; j++) v[j] = (i0 + j < nb) ? deg2[i0 + j] : 0;
    int s = v[0] + v[1] + v[2] + v[3];
    ts[t] = s; __syncthreads();
    for (int d = 1; d < 256; d <<= 1) {
        int x = (t >= d) ? ts[t - d] : 0;
        __syncthreads();
        ts[t] += x;
        __syncthreads();
    }
    int run = bsum[blockIdx.x] + ts[t] - s;
    #pragma unroll
    for (int j = 0; j < 4; j++) {
        if (i0 + j < nb) { rowptr2[i0 + j] = run; cursor2[i0 + j] = run; run += v[j]; }
    }
}

__global__ void fill2_kernel(const int* __restrict__ et, const int* __restrict__ eidx,
                             int E, int N, int* __restrict__ cursor2, int* __restrict__ order) {
    for (int i = blockIdx.x * blockDim.x + threadIdx.x; i < E; i += gridDim.x * blockDim.x) {
        int pos = atomicAdd(&cursor2[et[i] * N + eidx[E + i]], 1);
        order[pos] = i;
    }
}

// ---------------- layer 1: Y[p][m] = relu(h_in[p] @ W1[t] + b1[t]),  bf16 out
// operand-swapped: A = W1^T (LDS), B = h_in rows (global gather), C'[m=hid][n=edge]
__global__ __launch_bounds__(512) void l1_kernel(
    const float* __restrict__ h, const int* __restrict__ eidx,
    const float* __restrict__ eattr, const float* __restrict__ W1,
    const float* __restrict__ b1, const int* __restrict__ order,
    const int* __restrict__ rowptr2, unsigned short* __restrict__ Yg, int E, int N)
{
    __shared__ unsigned short W1T[128 * W1T_LD];
    __shared__ float b1s[128];
    const int t = blockIdx.x & 3;
    const int lb = blockIdx.x >> 2;
    const int nb = gridDim.x >> 2;
    const int tid = threadIdx.x;

    for (int idx = tid; idx < K1 * Hh; idx += 512) {
        int k = idx >> 7, n = idx & 127;
        W1T[n * W1T_LD + k] = f2bf(W1[((size_t)t * K1 + k) * Hh + n]);
    }
    for (int idx = tid; idx < (W1T_LD - K1) * Hh; idx += 512) {
        int k = K1 + (idx % (W1T_LD - K1)), n = idx / (W1T_LD - K1);
        W1T[n * W1T_LD + k] = 0;   // zero pad k=144..167 (read up to 159)
    }
    if (tid < 128) b1s[tid] = b1[t * Hh + tid];
    __syncthreads();

    const int tstart = rowptr2[(size_t)t * N];
    const int tend = rowptr2[(size_t)(t + 1) * N];
    const int cnt = tend - tstart;
    const int ntiles = (cnt + 255) >> 8;
    const int w = tid >> 6, lane = tid & 63;
    const int l15 = lane & 15, q = lane >> 4;

    for (int tile = lb; tile < ntiles; tile += nb) {
        const int p0 = tstart + tile * 256 + w * 32;
        const int pa = p0 + l15, pb = p0 + 16 + l15;
        const bool va = pa < tend, vb = pb < tend;
        const int ea = order[va ? pa : tstart];
        const int eb = order[vb ? pb : tstart];
        const int sa = eidx[ea], sb = eidx[eb];
        const float* __restrict__ hA = h + (size_t)sa * Hh;
        const float* __restrict__ hB = h + (size_t)sb * Hh;

        f32x4 acc[8][2];
        #pragma unroll
        for (int mt = 0; mt < 8; mt++) {
            acc[mt][0] = (f32x4){0.f, 0.f, 0.f, 0.f};
            acc[mt][1] = (f32x4){0.f, 0.f, 0.f, 0.f};
        }

        #pragma unroll
        for (int ks = 0; ks < 5; ks++) {
            const int k0 = ks * 32;
            bf16x8 fb_a, fb_b;
            if (ks < 4) {
                fb_a = pack8(hA + k0 + q * 8);
                fb_b = pack8(hB + k0 + q * 8);
            } else if (q < 2) {
                fb_a = pack8(eattr + (size_t)ea * Aa + q * 8);
                fb_b = pack8(eattr + (size_t)eb * Aa + q * 8);
            } else {
                fb_a = zero_bf8();
                fb_b = zero_bf8();
            }
            #pragma unroll
            for (int mt = 0; mt < 8; mt++) {
                bf16x8 fa = *(const bf16x8*)&W1T[(mt * 16 + l15) * W1T_LD + k0 + q * 8];
                acc[mt][0] = __builtin_amdgcn_mfma_f32_16x16x32_bf16(fa, fb_a, acc[mt][0], 0, 0, 0);
                acc[mt][1] = __builtin_amdgcn_mfma_f32_16x16x32_bf16(fa, fb_b, acc[mt][1], 0, 0, 0);
            }
        }

        #pragma unroll
        for (int mt = 0; mt < 8; mt++) {
            f32x4 bias = *(const f32x4*)&b1s[mt * 16 + q * 4];
            if (va) {
                u16x4 y;
                #pragma unroll
                for (int i = 0; i < 4; i++) {
                    float v = acc[mt][0][i] + bias[i];
                    y[i] = f2bf(v > 0.f ? v : 0.f);
                }
                *(u16x4*)&Yg[(size_t)pa * Hh + mt * 16 + q * 4] = y;
            }
            if (vb) {
                u16x4 y;
                #pragma unroll
                for (int i = 0; i < 4; i++) {
                    float v = acc[mt][1][i] + bias[i];
                    y[i] = f2bf(v > 0.f ? v : 0.f);
                }
                *(u16x4*)&Yg[(size_t)pb * Hh + mt * 16 + q * 4] = y;
            }
        }
    }
}

// ---------------- fused segment-sum + second GEMM:
// msg[n] = sum_t (sum_{e in (t,n)-segment} Y[e]) @ W2[t] + cnt[n,t]*b2[t]
// Segments are contiguous in Yg because edges are sorted by (type, dst).
__global__ __launch_bounds__(256) void zgemm_kernel(
    const unsigned short* __restrict__ Yg, const int* __restrict__ rowptr2,
    const float* __restrict__ W2, const float* __restrict__ b2,
    float* __restrict__ msg, int N)
{
    __shared__ unsigned short W2T[128 * WG_LD];
    __shared__ float b2s[512];
    __shared__ int cntS[4 * 64];   // [wave][t*16 + l15]
    const int tid = threadIdx.x;
    const int w = tid >> 6, lane = tid & 63;
    const int l15 = lane & 15, q = lane >> 4;
    const int nodebase = blockIdx.x * 64 + w * 16;
    const int nA = min(nodebase + l15, N - 1);

    if (tid < 512) {
        // 256 threads -> two rounds
        b2s[tid] = b2[tid];
        b2s[tid + 256] = b2[tid + 256];
    }

    f32x4 acc[8];
    #pragma unroll
    for (int ct = 0; ct < 8; ct++) acc[ct] = (f32x4){0.f, 0.f, 0.f, 0.f};

    for (int t = 0; t < Tt; t++) {
        __syncthreads();
        for (int idx = tid; idx < Hh * Hh; idx += 256) {
            int k = idx >> 7, n = idx & 127;
            W2T[n * WG_LD + k] = f2bf(W2[((size_t)t * Hh + k) * Hh + n]);
        }
        __syncthreads();

        const int seg = rowptr2[(size_t)t * N + nA];
        const int len = rowptr2[(size_t)t * N + nA + 1] - seg;
        cntS[w * 64 + t * 16 + l15] = len;

        float asum[32];
        #pragma unroll
        for (int i = 0; i < 32; i++) asum[i] = 0.f;
        for (int j = 0; j < len; j++) {
            const unsigned short* __restrict__ yr = Yg + (size_t)(seg + j) * Hh;
            #pragma unroll
            for (int ks = 0; ks < 4; ks++) {
                u16x8 yv = *(const u16x8*)(yr + ks * 32 + q * 8);
                #pragma unroll
                for (int e = 0; e < 8; e++) asum[ks * 8 + e] += bf2f(yv[e]);
            }
        }

        #pragma unroll
        for (int ks = 0; ks < 4; ks++) {
            u16x8 fr;
            #pragma unroll
            for (int e = 0; e < 8; e++) fr[e] = f2bf(asum[ks * 8 + e]);
            bf16x8 fa = __builtin_bit_cast(bf16x8, fr);
            #pragma unroll
            for (int ct = 0; ct < 8; ct++) {
                bf16x8 fb = *(const bf16x8*)&W2T[(ct * 16 + l15) * WG_LD + ks * 32 + q * 8];
                acc[ct] = __builtin_amdgcn_mfma_f32_16x16x32_bf16(fa, fb, acc[ct], 0, 0, 0);
            }
        }
    }
    __syncthreads();   // drain LDS writes (cntS) before epilogue reads

    #pragma unroll
    for (int ct = 0; ct < 8; ct++) {
        const int c = ct * 16 + l15;
        #pragma unroll
        for (int i = 0; i < 4; i++) {
            int node = nodebase + q * 4 + i;
            if (node < N) {
                float bias = 0.f;
                #pragma unroll
                for (int t = 0; t < Tt; t++)
                    bias += (float)cntS[w * 64 + t * 16 + q * 4 + i] * b2s[t * 128 + c];
                msg[(size_t)node * Hh + c] = acc[ct][i] + bias;
            }
        }
    }
}

// ---------------- GRU: out = (1-z)*n + z*h, gate-by-gate LDS weight staging
__global__ __launch_bounds__(512) void gru_kernel(
    const float* __restrict__ h, const float* __restrict__ msg,
    const float* __restrict__ w_ih, const float* __restrict__ w_hh,
    const float* __restrict__ b_ih, const float* __restrict__ b_hh,
    float* __restrict__ out, int N)
{
    __shared__ unsigned short Wg[128 * WG_LD];
    const int tid = threadIdx.x;
    const int w = tid >> 6, lane = tid & 63;
    const int l15 = lane & 15, q = lane >> 4;
    const int nodebase = blockIdx.x * 128 + w * 16;
    const int nA = min(nodebase + l15, N - 1);
    const float* __restrict__ mrow = msg + (size_t)nA * Hh;
    const float* __restrict__ hrow = h + (size_t)nA * Hh;

    f32x4 gr[8], gz[8], gin[8], ghn[8];
    #pragma unroll
    for (int ct = 0; ct < 8; ct++) {
        gr[ct] = (f32x4){0.f, 0.f, 0.f, 0.f};
        gz[ct] = (f32x4){0.f, 0.f, 0.f, 0.f};
        gin[ct] = (f32x4){0.f, 0.f, 0.f, 0.f};
        ghn[ct] = (f32x4){0.f, 0.f, 0.f, 0.f};
    }

    auto stage = [&](const float* __restrict__ Ws, int gate) {
        __syncthreads();
        for (int idx = tid; idx < Hh * Hh; idx += 512) {
            int o = idx >> 7, k = idx & 127;
            Wg[o * WG_LD + k] = f2bf(Ws[((size_t)gate * Hh + o) * Hh + k]);
        }
        __syncthreads();
    };
    auto matmul = [&](const float* __restrict__ arow, f32x4* acc) {
        #pragma unroll
        for (int ks = 0; ks < 4; ks++) {
            bf16x8 fa = pack8(arow + ks * 32 + q * 8);
            #pragma unroll
            for (int ct = 0; ct < 8; ct++) {
                bf16x8 fb = *(const bf16x8*)&Wg[(ct * 16 + l15) * WG_LD + ks * 32 + q * 8];
                acc[ct] = __builtin_amdgcn_mfma_f32_16x16x32_bf16(fa, fb, acc[ct], 0, 0, 0);
            }
        }
    };

    stage(w_ih, 0); matmul(mrow, gr);
    stage(w_hh, 0); matmul(hrow, gr);
    stage(w_ih, 1); matmul(mrow, gz);
    stage(w_hh, 1); matmul(hrow, gz);
    stage(w_ih, 2); matmul(mrow, gin);
    stage(w_hh, 2); matmul(hrow, ghn);

    #pragma unroll
    for (int ct = 0; ct < 8; ct++) {
        int c = ct * 16 + l15;
        float bir = b_ih[c],       bhr = b_hh[c];
        float biz = b_ih[128 + c], bhz = b_hh[128 + c];
        float bin = b_ih[256 + c], bhn = b_hh[256 + c];
        #pragma unroll
        for (int i = 0; i < 4; i++) {
            int node = nodebase + q * 4 + i;
            if (node < N) {
                float rv = 1.f / (1.f + __expf(-(gr[ct][i] + bir + bhr)));
                float zv = 1.f / (1.f + __expf(-(gz[ct][i] + biz + bhz)));
                float npre = gin[ct][i] + bin + rv * (ghn[ct][i] + bhn);
                float e2 = __expf(-2.f * npre);
                float nv = (1.f - e2) / (1.f + e2);
                float hv = h[(size_t)node * Hh + c];
                out[(size_t)node * Hh + c] = (1.f - zv) * nv + zv * hv;
            }
        }
    }
}

static inline size_t align256(size_t x) { return (x + 255) & ~(size_t)255; }

extern "C" void kernel_launch(void* const* d_in, const int* in_sizes, int n_in,
                              void* d_out, int out_size, void* d_ws, size_t ws_size,
                              hipStream_t stream)
{
    const float* h     = (const float*)d_in[0];
    const int*   eidx  = (const int*)d_in[1];
    const int*   et    = (const int*)d_in[2];
    const float* eattr = (const float*)d_in[3];
    const float* W1    = (const float*)d_in[4];
    const float* b1    = (const float*)d_in[5];
    const float* W2    = (const float*)d_in[6];
    const float* b2    = (const float*)d_in[7];
    const float* w_ih  = (const float*)d_in[8];
    const float* w_hh  = (const float*)d_in[9];
    const float* b_ih  = (const float*)d_in[10];
    const float* b_hh  = (const float*)d_in[11];

    const int N = in_sizes[0] / Hh;
    const int E = in_sizes[1] / 2;
    const int nb = 4 * N;                       // (type, dst) bins
    const int sblocks = (nb + 1023) / 1024;     // <= 256 required by scanB

    char* p = (char*)d_ws;
    float* msg = (float*)p;             p += align256((size_t)N * Hh * sizeof(float));
    unsigned short* Yg = (unsigned short*)p; p += align256((size_t)E * Hh * sizeof(unsigned short));
    int* order = (int*)p;               p += align256((size_t)E * sizeof(int));
    int* rowptr2 = (int*)p;             p += align256(((size_t)nb + 1) * sizeof(int));
    int* deg2 = (int*)p;                p += align256((size_t)nb * sizeof(int));
    int* cursor2 = (int*)p;             p += align256((size_t)nb * sizeof(int));
    int* bsum = (int*)p;                p += align256(1024 * sizeof(int));

    hipMemsetAsync(deg2, 0, (size_t)nb * sizeof(int), stream);

    hist_kernel<<<1024, 256, 0, stream>>>(et, eidx, E, N, deg2);
    scanA_kernel<<<sblocks, 256, 0, stream>>>(deg2, nb, bsum);
    scanB_kernel<<<1, 256, 0, stream>>>(bsum, sblocks, rowptr2, nb);
    scanC_kernel<<<sblocks, 256, 0, stream>>>(deg2, nb, bsum, rowptr2, cursor2);
    fill2_kernel<<<1024, 256, 0, stream>>>(et, eidx, E, N, cursor2, order);

    l1_kernel<<<1024, 512, 0, stream>>>(h, eidx, eattr, W1, b1, order, rowptr2, Yg, E, N);
    zgemm_kernel<<<(N + 63) / 64, 256, 0, stream>>>(Yg, rowptr2, W2, b2, msg, N);

    int gblocks = (N + 127) / 128;
    gru_kernel<<<gblocks, 512, 0, stream>>>(h, msg, w_ih, w_hh, b_ih, b_hh, (float*)d_out, N);
}

// Round 4
// 593.778 us; speedup vs baseline: 10.2437x; 1.0783x over previous
//
#include <hip/hip_runtime.h>
#include <stdint.h>

#define Hh 128
#define Aa 16
#define Tt 4
#define K1 144
#define W1T_LD 168   // pad: stride 336B -> bank advance 20 dw -> 2-way (free)
#define WG_LD  136   // pad: stride 272B -> bank advance 4 dw  -> 2-way (free)

typedef float f32x4 __attribute__((ext_vector_type(4)));
typedef __bf16 bf16x8 __attribute__((ext_vector_type(8)));
typedef unsigned short u16x8 __attribute__((ext_vector_type(8)));
typedef unsigned short u16x4 __attribute__((ext_vector_type(4)));

static __device__ __forceinline__ unsigned short f2bf(float f) {
    unsigned u = __builtin_bit_cast(unsigned, f);
    u += 0x7fffu + ((u >> 16) & 1u);   // RNE
    return (unsigned short)(u >> 16);
}

static __device__ __forceinline__ float bf2f(unsigned short u) {
    return __builtin_bit_cast(float, (unsigned)u << 16);
}

static __device__ __forceinline__ bf16x8 pack8(const float* __restrict__ x) {
    f32x4 a = *(const f32x4*)x;
    f32x4 b = *(const f32x4*)(x + 4);
    u16x8 t;
    t[0] = f2bf(a[0]); t[1] = f2bf(a[1]); t[2] = f2bf(a[2]); t[3] = f2bf(a[3]);
    t[4] = f2bf(b[0]); t[5] = f2bf(b[1]); t[6] = f2bf(b[2]); t[7] = f2bf(b[3]);
    return __builtin_bit_cast(bf16x8, t);
}

static __device__ __forceinline__ bf16x8 zero_bf8() {
    u16x8 z = {0, 0, 0, 0, 0, 0, 0, 0};
    return __builtin_bit_cast(bf16x8, z);
}

// ============ bf16 pre-cast (one pass; removes per-gather f32->bf16 and halves gather bytes)
__global__ void cast_kernel(const float* __restrict__ src, unsigned short* __restrict__ dst, int n4) {
    int i = blockIdx.x * blockDim.x + threadIdx.x;
    if (i < n4) {
        f32x4 v = *(const f32x4*)(src + (size_t)i * 4);
        u16x4 o;
        o[0] = f2bf(v[0]); o[1] = f2bf(v[1]); o[2] = f2bf(v[2]); o[3] = f2bf(v[3]);
        *(u16x4*)(dst + (size_t)i * 4) = o;
    }
}

// ============ bucketing by (type, dst): 4N bins, exclusive scan -> rowptr2 ============
__global__ void hist_kernel(const int* __restrict__ et, const int* __restrict__ eidx,
                            int E, int N, int* __restrict__ deg2) {
    for (int i = blockIdx.x * blockDim.x + threadIdx.x; i < E; i += gridDim.x * blockDim.x)
        atomicAdd(&deg2[et[i] * N + eidx[E + i]], 1);   // ~4 colliders/bin avg
}

// per-1024-chunk block sums
__global__ void scanA_kernel(const int* __restrict__ deg2, int nb, int* __restrict__ bsum) {
    __shared__ int red[256];
    const int t = threadIdx.x;
    const int i0 = blockIdx.x * 1024 + t * 4;
    int s = 0;
    #pragma unroll
    for (int j = 0; j < 4; j++) if (i0 + j < nb) s += deg2[i0 + j];
    red[t] = s; __syncthreads();
    for (int d = 128; d > 0; d >>= 1) {
        if (t < d) red[t] += red[t + d];
        __syncthreads();
    }
    if (t == 0) bsum[blockIdx.x] = red[0];
}

// single-block exclusive scan of block sums (nblocks <= 256)
__global__ void scanB_kernel(int* __restrict__ bsum, int nblocks,
                             int* __restrict__ rowptr2, int nb) {
    __shared__ int ts[256];
    const int t = threadIdx.x;
    int v = (t < nblocks) ? bsum[t] : 0;
    ts[t] = v; __syncthreads();
    for (int d = 1; d < 256; d <<= 1) {
        int x = (t >= d) ? ts[t - d] : 0;
        __syncthreads();
        ts[t] += x;
        __syncthreads();
    }
    if (t < nblocks) bsum[t] = ts[t] - v;   // exclusive
    if (t == 255) rowptr2[nb] = ts[255];    // total == E
}

// per-chunk exclusive scan + global offset; writes rowptr2 and cursor copy
__global__ void scanC_kernel(const int* __restrict__ deg2, int nb,
                             const int* __restrict__ bsum,
                             int* __restrict__ rowptr2, int* __restrict__ cursor2) {
    __shared__ int ts[256];
    const int t = threadIdx.x;
    const int i0 = blockIdx.x * 1024 + t * 4;
    int v[4];
    #pragma unroll
    for (int j = 0; j < 4; j++) v[j] = (i0 + j < nb) ? deg2[i0 + j] : 0;
    int s = v[0] + v[1] + v[2] + v[3];
    ts[t] = s; __syncthreads();
    for (int d = 1; d < 256; d <<= 1) {
        int x = (t >= d) ? ts[t - d] : 0;
        __syncthreads();
        ts[t] += x;
        __syncthreads();
    }
    int run = bsum[blockIdx.x] + ts[t] - s;
    #pragma unroll
    for (int j = 0; j < 4; j++) {
        if (i0 + j < nb) { rowptr2[i0 + j] = run; cursor2[i0 + j] = run; run += v[j]; }
    }
}

__global__ void fill2_kernel(const int* __restrict__ et, const int* __restrict__ eidx,
                             int E, int N, int* __restrict__ cursor2, int* __restrict__ order) {
    for (int i = blockIdx.x * blockDim.x + threadIdx.x; i < E; i += gridDim.x * blockDim.x) {
        int pos = atomicAdd(&cursor2[et[i] * N + eidx[E + i]], 1);
        order[pos] = i;
    }
}

// ---------------- layer 1: Y[p][m] = relu(h_in[p] @ W1[t] + b1[t]),  bf16 out
// operand-swapped: A = W1^T (LDS), B = h_in rows (bf16 global gather), C'[m=hid][n=edge]
__global__ __launch_bounds__(512) void l1_kernel(
    const unsigned short* __restrict__ h_bf, const int* __restrict__ eidx,
    const float* __restrict__ eattr, const unsigned short* __restrict__ W1bf,
    const float* __restrict__ b1, const int* __restrict__ order,
    const int* __restrict__ rowptr2, unsigned short* __restrict__ Yg, int E, int N)
{
    __shared__ unsigned short W1T[128 * W1T_LD];
    __shared__ float b1s[128];
    const int t = blockIdx.x & 3;
    const int lb = blockIdx.x >> 2;
    const int nb = gridDim.x >> 2;
    const int tid = threadIdx.x;

    for (int idx = tid; idx < K1 * Hh; idx += 512) {
        int k = idx >> 7, n = idx & 127;
        W1T[n * W1T_LD + k] = W1bf[((size_t)t * K1 + k) * Hh + n];
    }
    for (int idx = tid; idx < (W1T_LD - K1) * Hh; idx += 512) {
        int k = K1 + (idx % (W1T_LD - K1)), n = idx / (W1T_LD - K1);
        W1T[n * W1T_LD + k] = 0;   // zero pad k=144..167 (read up to 159)
    }
    if (tid < 128) b1s[tid] = b1[t * Hh + tid];
    __syncthreads();

    const int tstart = rowptr2[(size_t)t * N];
    const int tend = rowptr2[(size_t)(t + 1) * N];
    const int cnt = tend - tstart;
    const int ntiles = (cnt + 255) >> 8;
    const int w = tid >> 6, lane = tid & 63;
    const int l15 = lane & 15, q = lane >> 4;

    for (int tile = lb; tile < ntiles; tile += nb) {
        const int p0 = tstart + tile * 256 + w * 32;
        const int pa = p0 + l15, pb = p0 + 16 + l15;
        const bool va = pa < tend, vb = pb < tend;
        const int ea = order[va ? pa : tstart];
        const int eb = order[vb ? pb : tstart];
        const int sa = eidx[ea], sb = eidx[eb];
        const unsigned short* __restrict__ hA = h_bf + (size_t)sa * Hh;
        const unsigned short* __restrict__ hB = h_bf + (size_t)sb * Hh;

        f32x4 acc[8][2];
        #pragma unroll
        for (int mt = 0; mt < 8; mt++) {
            acc[mt][0] = (f32x4){0.f, 0.f, 0.f, 0.f};
            acc[mt][1] = (f32x4){0.f, 0.f, 0.f, 0.f};
        }

        #pragma unroll
        for (int ks = 0; ks < 5; ks++) {
            const int k0 = ks * 32;
            bf16x8 fb_a, fb_b;
            if (ks < 4) {
                fb_a = __builtin_bit_cast(bf16x8, *(const u16x8*)(hA + k0 + q * 8));
                fb_b = __builtin_bit_cast(bf16x8, *(const u16x8*)(hB + k0 + q * 8));
            } else if (q < 2) {
                fb_a = pack8(eattr + (size_t)ea * Aa + q * 8);
                fb_b = pack8(eattr + (size_t)eb * Aa + q * 8);
            } else {
                fb_a = zero_bf8();
                fb_b = zero_bf8();
            }
            #pragma unroll
            for (int mt = 0; mt < 8; mt++) {
                bf16x8 fa = *(const bf16x8*)&W1T[(mt * 16 + l15) * W1T_LD + k0 + q * 8];
                acc[mt][0] = __builtin_amdgcn_mfma_f32_16x16x32_bf16(fa, fb_a, acc[mt][0], 0, 0, 0);
                acc[mt][1] = __builtin_amdgcn_mfma_f32_16x16x32_bf16(fa, fb_b, acc[mt][1], 0, 0, 0);
            }
        }

        #pragma unroll
        for (int mt = 0; mt < 8; mt++) {
            f32x4 bias = *(const f32x4*)&b1s[mt * 16 + q * 4];
            if (va) {
                u16x4 y;
                #pragma unroll
                for (int i = 0; i < 4; i++) {
                    float v = acc[mt][0][i] + bias[i];
                    y[i] = f2bf(v > 0.f ? v : 0.f);
                }
                *(u16x4*)&Yg[(size_t)pa * Hh + mt * 16 + q * 4] = y;
            }
            if (vb) {
                u16x4 y;
                #pragma unroll
                for (int i = 0; i < 4; i++) {
                    float v = acc[mt][1][i] + bias[i];
                    y[i] = f2bf(v > 0.f ? v : 0.f);
                }
                *(u16x4*)&Yg[(size_t)pb * Hh + mt * 16 + q * 4] = y;
            }
        }
    }
}

// ---------------- fused segment-sum + second GEMM:
// msg[n] = sum_t (sum_{e in (t,n)-segment} Y[e]) @ W2[t] + cnt[n,t]*b2[t]
// Segments are contiguous in Yg because edges are sorted by (type, dst).
__global__ __launch_bounds__(256) void zgemm_kernel(
    const unsigned short* __restrict__ Yg, const int* __restrict__ rowptr2,
    const unsigned short* __restrict__ W2bf, const float* __restrict__ b2,
    float* __restrict__ msg, int N)
{
    __shared__ unsigned short W2T[128 * WG_LD];
    __shared__ float b2s[512];
    __shared__ int cntS[4 * 64];   // [wave][t*16 + l15]
    const int tid = threadIdx.x;
    const int w = tid >> 6, lane = tid & 63;
    const int l15 = lane & 15, q = lane >> 4;
    const int nodebase = blockIdx.x * 64 + w * 16;
    const int nA = min(nodebase + l15, N - 1);

    if (tid < 512) {
        // 256 threads -> two rounds
        b2s[tid] = b2[tid];
        b2s[tid + 256] = b2[tid + 256];
    }

    f32x4 acc[8];
    #pragma unroll
    for (int ct = 0; ct < 8; ct++) acc[ct] = (f32x4){0.f, 0.f, 0.f, 0.f};

    for (int t = 0; t < Tt; t++) {
        __syncthreads();
        for (int idx = tid; idx < Hh * Hh; idx += 256) {
            int k = idx >> 7, n = idx & 127;
            W2T[n * WG_LD + k] = W2bf[((size_t)t * Hh + k) * Hh + n];
        }
        __syncthreads();

        const int seg = rowptr2[(size_t)t * N + nA];
        const int len = rowptr2[(size_t)t * N + nA + 1] - seg;
        cntS[w * 64 + t * 16 + l15] = len;

        float asum[32];
        #pragma unroll
        for (int i = 0; i < 32; i++) asum[i] = 0.f;
        for (int j = 0; j < len; j++) {
            const unsigned short* __restrict__ yr = Yg + (size_t)(seg + j) * Hh;
            #pragma unroll
            for (int ks = 0; ks < 4; ks++) {
                u16x8 yv = *(const u16x8*)(yr + ks * 32 + q * 8);
                #pragma unroll
                for (int e = 0; e < 8; e++) asum[ks * 8 + e] += bf2f(yv[e]);
            }
        }

        #pragma unroll
        for (int ks = 0; ks < 4; ks++) {
            u16x8 fr;
            #pragma unroll
            for (int e = 0; e < 8; e++) fr[e] = f2bf(asum[ks * 8 + e]);
            bf16x8 fa = __builtin_bit_cast(bf16x8, fr);
            #pragma unroll
            for (int ct = 0; ct < 8; ct++) {
                bf16x8 fb = *(const bf16x8*)&W2T[(ct * 16 + l15) * WG_LD + ks * 32 + q * 8];
                acc[ct] = __builtin_amdgcn_mfma_f32_16x16x32_bf16(fa, fb, acc[ct], 0, 0, 0);
            }
        }
    }
    __syncthreads();   // drain LDS writes (cntS) before epilogue reads

    #pragma unroll
    for (int ct = 0; ct < 8; ct++) {
        const int c = ct * 16 + l15;
        #pragma unroll
        for (int i = 0; i < 4; i++) {
            int node = nodebase + q * 4 + i;
            if (node < N) {
                float bias = 0.f;
                #pragma unroll
                for (int t = 0; t < Tt; t++)
                    bias += (float)cntS[w * 64 + t * 16 + q * 4 + i] * b2s[t * 128 + c];
                msg[(size_t)node * Hh + c] = acc[ct][i] + bias;
            }
        }
    }
}

// ---------------- GRU: out = (1-z)*n + z*h, gate-by-gate LDS weight staging
__global__ __launch_bounds__(512) void gru_kernel(
    const float* __restrict__ h, const float* __restrict__ msg,
    const float* __restrict__ w_ih, const float* __restrict__ w_hh,
    const float* __restrict__ b_ih, const float* __restrict__ b_hh,
    float* __restrict__ out, int N)
{
    __shared__ unsigned short Wg[128 * WG_LD];
    const int tid = threadIdx.x;
    const int w = tid >> 6, lane = tid & 63;
    const int l15 = lane & 15, q = lane >> 4;
    const int nodebase = blockIdx.x * 128 + w * 16;
    const int nA = min(nodebase + l15, N - 1);
    const float* __restrict__ mrow = msg + (size_t)nA * Hh;
    const float* __restrict__ hrow = h + (size_t)nA * Hh;

    f32x4 gr[8], gz[8], gin[8], ghn[8];
    #pragma unroll
    for (int ct = 0; ct < 8; ct++) {
        gr[ct] = (f32x4){0.f, 0.f, 0.f, 0.f};
        gz[ct] = (f32x4){0.f, 0.f, 0.f, 0.f};
        gin[ct] = (f32x4){0.f, 0.f, 0.f, 0.f};
        ghn[ct] = (f32x4){0.f, 0.f, 0.f, 0.f};
    }

    auto stage = [&](const float* __restrict__ Ws, int gate) {
        __syncthreads();
        for (int idx = tid; idx < Hh * Hh; idx += 512) {
            int o = idx >> 7, k = idx & 127;
            Wg[o * WG_LD + k] = f2bf(Ws[((size_t)gate * Hh + o) * Hh + k]);
        }
        __syncthreads();
    };
    auto matmul = [&](const float* __restrict__ arow, f32x4* acc) {
        #pragma unroll
        for (int ks = 0; ks < 4; ks++) {
            bf16x8 fa = pack8(arow + ks * 32 + q * 8);
            #pragma unroll
            for (int ct = 0; ct < 8; ct++) {
                bf16x8 fb = *(const bf16x8*)&Wg[(ct * 16 + l15) * WG_LD + ks * 32 + q * 8];
                acc[ct] = __builtin_amdgcn_mfma_f32_16x16x32_bf16(fa, fb, acc[ct], 0, 0, 0);
            }
        }
    };

    stage(w_ih, 0); matmul(mrow, gr);
    stage(w_hh, 0); matmul(hrow, gr);
    stage(w_ih, 1); matmul(mrow, gz);
    stage(w_hh, 1); matmul(hrow, gz);
    stage(w_ih, 2); matmul(mrow, gin);
    stage(w_hh, 2); matmul(hrow, ghn);

    #pragma unroll
    for (int ct = 0; ct < 8; ct++) {
        int c = ct * 16 + l15;
        float bir = b_ih[c],       bhr = b_hh[c];
        float biz = b_ih[128 + c], bhz = b_hh[128 + c];
        float bin = b_ih[256 + c], bhn = b_hh[256 + c];
        #pragma unroll
        for (int i = 0; i < 4; i++) {
            int node = nodebase + q * 4 + i;
            if (node < N) {
                float rv = 1.f / (1.f + __expf(-(gr[ct][i] + bir + bhr)));
                float zv = 1.f / (1.f + __expf(-(gz[ct][i] + biz + bhz)));
                float npre = gin[ct][i] + bin + rv * (ghn[ct][i] + bhn);
                float e2 = __expf(-2.f * npre);
                float nv = (1.f - e2) / (1.f + e2);
                float hv = h[(size_t)node * Hh + c];
                out[(size_t)node * Hh + c] = (1.f - zv) * nv + zv * hv;
            }
        }
    }
}

static inline size_t align256(size_t x) { return (x + 255) & ~(size_t)255; }

extern "C" void kernel_launch(void* const* d_in, const int* in_sizes, int n_in,
                              void* d_out, int out_size, void* d_ws, size_t ws_size,
                              hipStream_t stream)
{
    const float* h     = (const float*)d_in[0];
    const int*   eidx  = (const int*)d_in[1];
    const int*   et    = (const int*)d_in[2];
    const float* eattr = (const float*)d_in[3];
    const float* W1    = (const float*)d_in[4];
    const float* b1    = (const float*)d_in[5];
    const float* W2    = (const float*)d_in[6];
    const float* b2    = (const float*)d_in[7];
    const float* w_ih  = (const float*)d_in[8];
    const float* w_hh  = (const float*)d_in[9];
    const float* b_ih  = (const float*)d_in[10];
    const float* b_hh  = (const float*)d_in[11];

    const int N = in_sizes[0] / Hh;
    const int E = in_sizes[1] / 2;
    const int nb = 4 * N;                       // (type, dst) bins
    const int sblocks = (nb + 1023) / 1024;     // <= 256 required by scanB

    char* p = (char*)d_ws;
    float* msg = (float*)p;             p += align256((size_t)N * Hh * sizeof(float));
    unsigned short* Yg = (unsigned short*)p; p += align256((size_t)E * Hh * sizeof(unsigned short));
    int* order = (int*)p;               p += align256((size_t)E * sizeof(int));
    int* rowptr2 = (int*)p;             p += align256(((size_t)nb + 1) * sizeof(int));
    int* deg2 = (int*)p;                p += align256((size_t)nb * sizeof(int));
    int* cursor2 = (int*)p;             p += align256((size_t)nb * sizeof(int));
    int* bsum = (int*)p;                p += align256(1024 * sizeof(int));
    unsigned short* h_bf = (unsigned short*)p; p += align256((size_t)N * Hh * sizeof(unsigned short));
    unsigned short* W1bf = (unsigned short*)p; p += align256((size_t)Tt * K1 * Hh * sizeof(unsigned short));
    unsigned short* W2bf = (unsigned short*)p; p += align256((size_t)Tt * Hh * Hh * sizeof(unsigned short));

    hipMemsetAsync(deg2, 0, (size_t)nb * sizeof(int), stream);

    // pre-cast to bf16 (n4 = count/4, all counts divisible by 4)
    {
        int n4h = N * Hh / 4, n41 = Tt * K1 * Hh / 4, n42 = Tt * Hh * Hh / 4;
        cast_kernel<<<(n4h + 255) / 256, 256, 0, stream>>>(h, h_bf, n4h);
        cast_kernel<<<(n41 + 255) / 256, 256, 0, stream>>>(W1, W1bf, n41);
        cast_kernel<<<(n42 + 255) / 256, 256, 0, stream>>>(W2, W2bf, n42);
    }

    hist_kernel<<<1024, 256, 0, stream>>>(et, eidx, E, N, deg2);
    scanA_kernel<<<sblocks, 256, 0, stream>>>(deg2, nb, bsum);
    scanB_kernel<<<1, 256, 0, stream>>>(bsum, sblocks, rowptr2, nb);
    scanC_kernel<<<sblocks, 256, 0, stream>>>(deg2, nb, bsum, rowptr2, cursor2);
    fill2_kernel<<<1024, 256, 0, stream>>>(et, eidx, E, N, cursor2, order);

    l1_kernel<<<1024, 512, 0, stream>>>(h_bf, eidx, eattr, W1bf, b1, order, rowptr2, Yg, E, N);
    zgemm_kernel<<<(N + 63) / 64, 256, 0, stream>>>(Yg, rowptr2, W2bf, b2, msg, N);

    int gblocks = (N + 127) / 128;
    gru_kernel<<<gblocks, 512, 0, stream>>>(h, msg, w_ih, w_hh, b_ih, b_hh, (float*)d_out, N);
}

// Round 7
// 571.081 us; speedup vs baseline: 10.6508x; 1.0397x over previous
//
#include <hip/hip_runtime.h>
#include <stdint.h>

#define Hh 128
#define Aa 16
#define Tt 4
#define K1 144
#define W1T_LD 168   // pad: stride 336B -> bank advance 20 dw -> 2-way (free)
#define WG_LD  136   // pad: stride 272B -> bank advance 4 dw  -> 2-way (free)
#define YT_LD  136   // epilogue tile row stride (u16): 16B-aligned rows, <=2-way banks

typedef float f32x4 __attribute__((ext_vector_type(4)));
typedef __bf16 bf16x8 __attribute__((ext_vector_type(8)));
typedef unsigned short u16x8 __attribute__((ext_vector_type(8)));
typedef unsigned short u16x4 __attribute__((ext_vector_type(4)));

static __device__ __forceinline__ unsigned short f2bf(float f) {
    unsigned u = __builtin_bit_cast(unsigned, f);
    u += 0x7fffu + ((u >> 16) & 1u);   // RNE
    return (unsigned short)(u >> 16);
}

static __device__ __forceinline__ float bf2f(unsigned short u) {
    return __builtin_bit_cast(float, (unsigned)u << 16);
}

static __device__ __forceinline__ bf16x8 pack8(const float* __restrict__ x) {
    f32x4 a = *(const f32x4*)x;
    f32x4 b = *(const f32x4*)(x + 4);
    u16x8 t;
    t[0] = f2bf(a[0]); t[1] = f2bf(a[1]); t[2] = f2bf(a[2]); t[3] = f2bf(a[3]);
    t[4] = f2bf(b[0]); t[5] = f2bf(b[1]); t[6] = f2bf(b[2]); t[7] = f2bf(b[3]);
    return __builtin_bit_cast(bf16x8, t);
}

static __device__ __forceinline__ bf16x8 zero_bf8() {
    u16x8 z = {0, 0, 0, 0, 0, 0, 0, 0};
    return __builtin_bit_cast(bf16x8, z);
}

// ============ bf16 pre-cast
__global__ void cast_kernel(const float* __restrict__ src, unsigned short* __restrict__ dst, int n4) {
    int i = blockIdx.x * blockDim.x + threadIdx.x;
    if (i < n4) {
        f32x4 v = *(const f32x4*)(src + (size_t)i * 4);
        u16x4 o;
        o[0] = f2bf(v[0]); o[1] = f2bf(v[1]); o[2] = f2bf(v[2]); o[3] = f2bf(v[3]);
        *(u16x4*)(dst + (size_t)i * 4) = o;
    }
}

// ============ dual bucketing: bins [0,4N) by (type,dst), bins [4N,8N) by (type,src)
// cur holds counts then cursors (aliased in-place).
__global__ void hist_kernel(const int* __restrict__ et, const int* __restrict__ eidx,
                            int E, int N, int* __restrict__ deg2) {
    for (int i = blockIdx.x * blockDim.x + threadIdx.x; i < E; i += gridDim.x * blockDim.x) {
        int tt = et[i];
        atomicAdd(&deg2[tt * N + eidx[E + i]], 1);
        atomicAdd(&deg2[4 * N + tt * N + eidx[i]], 1);
    }
}

// per-1024-chunk block sums
__global__ void scanA_kernel(const int* __restrict__ deg2, int nb, int* __restrict__ bsum) {
    __shared__ int red[256];
    const int t = threadIdx.x;
    const int i0 = blockIdx.x * 1024 + t * 4;
    int s = 0;
    #pragma unroll
    for (int j = 0; j < 4; j++) if (i0 + j < nb) s += deg2[i0 + j];
    red[t] = s; __syncthreads();
    for (int d = 128; d > 0; d >>= 1) {
        if (t < d) red[t] += red[t + d];
        __syncthreads();
    }
    if (t == 0) bsum[blockIdx.x] = red[0];
}

// single-block exclusive scan of block sums (nblocks <= 512); also closes dst rowptr
__global__ void scanB_kernel(int* __restrict__ bsum, int nblocks,
                             int* __restrict__ rowptrD, int fourN, int E) {
    __shared__ int ts[512];
    const int t = threadIdx.x;
    int v = (t < nblocks) ? bsum[t] : 0;
    ts[t] = v; __syncthreads();
    for (int d = 1; d < 512; d <<= 1) {
        int x = (t >= d) ? ts[t - d] : 0;
        __syncthreads();
        ts[t] += x;
        __syncthreads();
    }
    if (t < nblocks) bsum[t] = ts[t] - v;   // exclusive
    if (t == 0) rowptrD[fourN] = E;         // dst half always sums to E
}

// per-chunk exclusive scan + global offset; rowptrD for dst bins, cursors in-place
__global__ void scanC_kernel(int* __restrict__ cur, int nb, int fourN,
                             const int* __restrict__ bsum, int* __restrict__ rowptrD) {
    __shared__ int ts[256];
    const int t = threadIdx.x;
    const int i0 = blockIdx.x * 1024 + t * 4;
    int v[4];
    #pragma unroll
    for (int j = 0; j < 4; j++) v[j] = (i0 + j < nb) ? cur[i0 + j] : 0;
    int s = v[0] + v[1] + v[2] + v[3];
    ts[t] = s; __syncthreads();
    for (int d = 1; d < 256; d <<= 1) {
        int x = (t >= d) ? ts[t - d] : 0;
        __syncthreads();
        ts[t] += x;
        __syncthreads();
    }
    int run = bsum[blockIdx.x] + ts[t] - s;
    #pragma unroll
    for (int j = 0; j < 4; j++) {
        if (i0 + j < nb) {
            if (i0 + j < fourN) rowptrD[i0 + j] = run;
            cur[i0 + j] = run;   // in-place over counts: each thread owns its 4 bins
            run += v[j];
        }
    }
}

// one pass: place edge in both orders; (type,src) order carries (src, eid, ydstpos)
__global__ void fill2_kernel(const int* __restrict__ et, const int* __restrict__ eidx,
                             int E, int N, int* __restrict__ cur,
                             int* __restrict__ srcS, int* __restrict__ eidS,
                             int* __restrict__ yposS) {
    for (int i = blockIdx.x * blockDim.x + threadIdx.x; i < E; i += gridDim.x * blockDim.x) {
        int tt = et[i];
        int d = eidx[E + i], s = eidx[i];
        int posD = atomicAdd(&cur[tt * N + d], 1);
        int posS = atomicAdd(&cur[4 * N + tt * N + s], 1) - E;
        srcS[posS] = s;
        eidS[posS] = i;
        yposS[posS] = posD;
    }
}

// ---------------- layer 1: iterate edges in (type,src) order -> sequential h gather;
// write Y rows to (type,dst) position via LDS-transposed full-line stores.
// BLOCK = 512 threads = 8 WAVES -> per-wave tile sized [8 waves][8 rows].
// LDS total: 43008 + 512 + 17408 = 60928 B (< 64 KB).
__global__ __launch_bounds__(512) void l1_kernel(
    const unsigned short* __restrict__ h_bf, const int* __restrict__ srcS,
    const int* __restrict__ eidS, const int* __restrict__ yposS,
    const float* __restrict__ eattr, const unsigned short* __restrict__ W1bf,
    const float* __restrict__ b1, const int* __restrict__ rowptrD,
    unsigned short* __restrict__ Yg, int N)
{
    __shared__ unsigned short W1T[128 * W1T_LD];
    __shared__ float b1s[128];
    __shared__ unsigned short yt[8 * 8 * YT_LD];   // 8 waves x 8 rows
    const int t = blockIdx.x & 3;
    const int lb = blockIdx.x >> 2;
    const int nbk = gridDim.x >> 2;
    const int tid = threadIdx.x;

    for (int idx = tid; idx < K1 * Hh; idx += 512) {
        int k = idx >> 7, n = idx & 127;
        W1T[n * W1T_LD + k] = W1bf[((size_t)t * K1 + k) * Hh + n];
    }
    for (int idx = tid; idx < (W1T_LD - K1) * Hh; idx += 512) {
        int k = K1 + (idx % (W1T_LD - K1)), n = idx / (W1T_LD - K1);
        W1T[n * W1T_LD + k] = 0;   // zero pad k=144..167 (read up to 159)
    }
    if (tid < 128) b1s[tid] = b1[t * Hh + tid];
    __syncthreads();

    // src-order segment of type t coincides positionally with dst-order boundaries
    const int tstart = rowptrD[t * N];
    const int tend = rowptrD[(t + 1) * N];
    const int cnt = tend - tstart;
    const int ntiles = (cnt + 255) >> 8;
    const int w = tid >> 6, lane = tid & 63;
    const int l15 = lane & 15, q = lane >> 4;
    unsigned short* __restrict__ ytw = yt + w * 8 * YT_LD;

    for (int tile = lb; tile < ntiles; tile += nbk) {
        const int p0 = tstart + tile * 256 + w * 32;
        const int pa = p0 + l15, pb = p0 + 16 + l15;
        const bool va = pa < tend, vb = pb < tend;
        const int spa = va ? pa : tstart;
        const int spb = vb ? pb : tstart;
        const int sa = srcS[spa], sb = srcS[spb];
        const int ea = eidS[spa], eb = eidS[spb];
        const int ypa = yposS[spa], ypb = yposS[spb];
        const unsigned short* __restrict__ hA = h_bf + (size_t)sa * Hh;
        const unsigned short* __restrict__ hB = h_bf + (size_t)sb * Hh;

        f32x4 acc[8][2];
        #pragma unroll
        for (int mt = 0; mt < 8; mt++) {
            acc[mt][0] = (f32x4){0.f, 0.f, 0.f, 0.f};
            acc[mt][1] = (f32x4){0.f, 0.f, 0.f, 0.f};
        }

        #pragma unroll
        for (int ks = 0; ks < 5; ks++) {
            const int k0 = ks * 32;
            bf16x8 fb_a, fb_b;
            if (ks < 4) {
                fb_a = __builtin_bit_cast(bf16x8, *(const u16x8*)(hA + k0 + q * 8));
                fb_b = __builtin_bit_cast(bf16x8, *(const u16x8*)(hB + k0 + q * 8));
            } else if (q < 2) {
                fb_a = pack8(eattr + (size_t)ea * Aa + q * 8);
                fb_b = pack8(eattr + (size_t)eb * Aa + q * 8);
            } else {
                fb_a = zero_bf8();
                fb_b = zero_bf8();
            }
            #pragma unroll
            for (int mt = 0; mt < 8; mt++) {
                bf16x8 fa = *(const bf16x8*)&W1T[(mt * 16 + l15) * W1T_LD + k0 + q * 8];
                acc[mt][0] = __builtin_amdgcn_mfma_f32_16x16x32_bf16(fa, fb_a, acc[mt][0], 0, 0, 0);
                acc[mt][1] = __builtin_amdgcn_mfma_f32_16x16x32_bf16(fa, fb_b, acc[mt][1], 0, 0, 0);
            }
        }

        // epilogue: 4 subpasses x 8 rows: bias+relu -> wave-private LDS tile ->
        // full-row 16B/lane stores to the edge's (type,dst) position.
        #pragma unroll
        for (int g = 0; g < 2; g++) {
            const int yp = g ? ypb : ypa;
            #pragma unroll
            for (int s = 0; s < 2; s++) {
                if ((l15 >> 3) == s) {
                    #pragma unroll
                    for (int mt = 0; mt < 8; mt++) {
                        f32x4 bias = *(const f32x4*)&b1s[mt * 16 + q * 4];
                        u16x4 y;
                        #pragma unroll
                        for (int i = 0; i < 4; i++) {
                            float v = acc[mt][g][i] + bias[i];
                            y[i] = f2bf(v > 0.f ? v : 0.f);
                        }
                        *(u16x4*)&ytw[(l15 & 7) * YT_LD + mt * 16 + q * 4] = y;
                    }
                }
                __asm__ volatile("s_waitcnt lgkmcnt(0)" ::: "memory");
                #pragma unroll
                for (int r0 = 0; r0 < 2; r0++) {
                    const int el = r0 * 4 + q;   // 0..7 within this 8-row subpass
                    if (p0 + g * 16 + s * 8 + el < tend) {
                        const int yrow = __shfl(yp, s * 8 + el);  // lane holds its edge's dst pos
                        u16x8 v = *(const u16x8*)&ytw[el * YT_LD + l15 * 8];
                        *(u16x8*)&Yg[(size_t)yrow * Hh + l15 * 8] = v;
                    }
                }
                __asm__ volatile("s_waitcnt lgkmcnt(0)" ::: "memory");
            }
        }
    }
}

// ---------------- fused segment-sum + second GEMM:
// msg[n] = sum_t (sum_{e in (t,n)-segment} Y[e]) @ W2[t] + cnt[n,t]*b2[t]   (bf16 out)
__global__ __launch_bounds__(256) void zgemm_kernel(
    const unsigned short* __restrict__ Yg, const int* __restrict__ rowptrD,
    const unsigned short* __restrict__ W2bf, const float* __restrict__ b2,
    unsigned short* __restrict__ msgb, int N)
{
    __shared__ unsigned short W2T[128 * WG_LD];
    __shared__ float b2s[512];
    __shared__ int cntS[4 * 64];   // [wave][t*16 + l15]
    const int tid = threadIdx.x;
    const int w = tid >> 6, lane = tid & 63;
    const int l15 = lane & 15, q = lane >> 4;
    const int nodebase = blockIdx.x * 64 + w * 16;
    const int nA = min(nodebase + l15, N - 1);

    if (tid < 512) {
        b2s[tid] = b2[tid];
        b2s[tid + 256] = b2[tid + 256];
    }

    f32x4 acc[8];
    #pragma unroll
    for (int ct = 0; ct < 8; ct++) acc[ct] = (f32x4){0.f, 0.f, 0.f, 0.f};

    for (int t = 0; t < Tt; t++) {
        __syncthreads();
        for (int idx = tid; idx < Hh * Hh; idx += 256) {
            int k = idx >> 7, n = idx & 127;
            W2T[n * WG_LD + k] = W2bf[((size_t)t * Hh + k) * Hh + n];
        }
        __syncthreads();

        const int seg = rowptrD[(size_t)t * N + nA];
        const int len = rowptrD[(size_t)t * N + nA + 1] - seg;
        cntS[w * 64 + t * 16 + l15] = len;

        float asum[32];
        #pragma unroll
        for (int i = 0; i < 32; i++) asum[i] = 0.f;
        for (int j = 0; j < len; j++) {
            const unsigned short* __restrict__ yr = Yg + (size_t)(seg + j) * Hh;
            #pragma unroll
            for (int ks = 0; ks < 4; ks++) {
                u16x8 yv = *(const u16x8*)(yr + ks * 32 + q * 8);
                #pragma unroll
                for (int e = 0; e < 8; e++) asum[ks * 8 + e] += bf2f(yv[e]);
            }
        }

        #pragma unroll
        for (int ks = 0; ks < 4; ks++) {
            u16x8 fr;
            #pragma unroll
            for (int e = 0; e < 8; e++) fr[e] = f2bf(asum[ks * 8 + e]);
            bf16x8 fa = __builtin_bit_cast(bf16x8, fr);
            #pragma unroll
            for (int ct = 0; ct < 8; ct++) {
                bf16x8 fb = *(const bf16x8*)&W2T[(ct * 16 + l15) * WG_LD + ks * 32 + q * 8];
                acc[ct] = __builtin_amdgcn_mfma_f32_16x16x32_bf16(fa, fb, acc[ct], 0, 0, 0);
            }
        }
    }
    __syncthreads();   // drain LDS writes (cntS) before epilogue reads

    #pragma unroll
    for (int ct = 0; ct < 8; ct++) {
        const int c = ct * 16 + l15;
        #pragma unroll
        for (int i = 0; i < 4; i++) {
            int node = nodebase + q * 4 + i;
            if (node < N) {
                float bias = 0.f;
                #pragma unroll
                for (int t = 0; t < Tt; t++)
                    bias += (float)cntS[w * 64 + t * 16 + q * 4 + i] * b2s[t * 128 + c];
                msgb[(size_t)node * Hh + c] = f2bf(acc[ct][i] + bias);
            }
        }
    }
}

// ---------------- GRU: out = (1-z)*n + z*h, gate-by-gate LDS weight staging
__global__ __launch_bounds__(512) void gru_kernel(
    const float* __restrict__ h, const unsigned short* __restrict__ msgb,
    const float* __restrict__ w_ih, const float* __restrict__ w_hh,
    const float* __restrict__ b_ih, const float* __restrict__ b_hh,
    float* __restrict__ out, int N)
{
    __shared__ unsigned short Wg[128 * WG_LD];
    const int tid = threadIdx.x;
    const int w = tid >> 6, lane = tid & 63;
    const int l15 = lane & 15, q = lane >> 4;
    const int nodebase = blockIdx.x * 128 + w * 16;
    const int nA = min(nodebase + l15, N - 1);
    const unsigned short* __restrict__ mrow = msgb + (size_t)nA * Hh;
    const float* __restrict__ hrow = h + (size_t)nA * Hh;

    f32x4 gr[8], gz[8], gin[8], ghn[8];
    #pragma unroll
    for (int ct = 0; ct < 8; ct++) {
        gr[ct] = (f32x4){0.f, 0.f, 0.f, 0.f};
        gz[ct] = (f32x4){0.f, 0.f, 0.f, 0.f};
        gin[ct] = (f32x4){0.f, 0.f, 0.f, 0.f};
        ghn[ct] = (f32x4){0.f, 0.f, 0.f, 0.f};
    }

    auto stage = [&](const float* __restrict__ Ws, int gate) {
        __syncthreads();
        for (int idx = tid; idx < Hh * Hh; idx += 512) {
            int o = idx >> 7, k = idx & 127;
            Wg[o * WG_LD + k] = f2bf(Ws[((size_t)gate * Hh + o) * Hh + k]);
        }
        __syncthreads();
    };
    auto matmulM = [&](f32x4* acc) {   // A rows from bf16 msg
        #pragma unroll
        for (int ks = 0; ks < 4; ks++) {
            bf16x8 fa = __builtin_bit_cast(bf16x8, *(const u16x8*)(mrow + ks * 32 + q * 8));
            #pragma unroll
            for (int ct = 0; ct < 8; ct++) {
                bf16x8 fb = *(const bf16x8*)&Wg[(ct * 16 + l15) * WG_LD + ks * 32 + q * 8];
                acc[ct] = __builtin_amdgcn_mfma_f32_16x16x32_bf16(fa, fb, acc[ct], 0, 0, 0);
            }
        }
    };
    auto matmulH = [&](f32x4* acc) {   // A rows from fp32 h
        #pragma unroll
        for (int ks = 0; ks < 4; ks++) {
            bf16x8 fa = pack8(hrow + ks * 32 + q * 8);
            #pragma unroll
            for (int ct = 0; ct < 8; ct++) {
                bf16x8 fb = *(const bf16x8*)&Wg[(ct * 16 + l15) * WG_LD + ks * 32 + q * 8];
                acc[ct] = __builtin_amdgcn_mfma_f32_16x16x32_bf16(fa, fb, acc[ct], 0, 0, 0);
            }
        }
    };

    stage(w_ih, 0); matmulM(gr);
    stage(w_hh, 0); matmulH(gr);
    stage(w_ih, 1); matmulM(gz);
    stage(w_hh, 1); matmulH(gz);
    stage(w_ih, 2); matmulM(gin);
    stage(w_hh, 2); matmulH(ghn);

    #pragma unroll
    for (int ct = 0; ct < 8; ct++) {
        int c = ct * 16 + l15;
        float bir = b_ih[c],       bhr = b_hh[c];
        float biz = b_ih[128 + c], bhz = b_hh[128 + c];
        float bin = b_ih[256 + c], bhn = b_hh[256 + c];
        #pragma unroll
        for (int i = 0; i < 4; i++) {
            int node = nodebase + q * 4 + i;
            if (node < N) {
                float rv = 1.f / (1.f + __expf(-(gr[ct][i] + bir + bhr)));
                float zv = 1.f / (1.f + __expf(-(gz[ct][i] + biz + bhz)));
                float npre = gin[ct][i] + bin + rv * (ghn[ct][i] + bhn);
                float e2 = __expf(-2.f * npre);
                float nv = (1.f - e2) / (1.f + e2);
                float hv = h[(size_t)node * Hh + c];
                out[(size_t)node * Hh + c] = (1.f - zv) * nv + zv * hv;
            }
        }
    }
}

static inline size_t align256(size_t x) { return (x + 255) & ~(size_t)255; }

extern "C" void kernel_launch(void* const* d_in, const int* in_sizes, int n_in,
                              void* d_out, int out_size, void* d_ws, size_t ws_size,
                              hipStream_t stream)
{
    const float* h     = (const float*)d_in[0];
    const int*   eidx  = (const int*)d_in[1];
    const int*   et    = (const int*)d_in[2];
    const float* eattr = (const float*)d_in[3];
    const float* W1    = (const float*)d_in[4];
    const float* b1    = (const float*)d_in[5];
    const float* W2    = (const float*)d_in[6];
    const float* b2    = (const float*)d_in[7];
    const float* w_ih  = (const float*)d_in[8];
    const float* w_hh  = (const float*)d_in[9];
    const float* b_ih  = (const float*)d_in[10];
    const float* b_hh  = (const float*)d_in[11];

    const int N = in_sizes[0] / Hh;
    const int E = in_sizes[1] / 2;
    const int nb = 8 * N;                       // [0,4N)=(type,dst), [4N,8N)=(type,src)
    const int sblocks = (nb + 1023) / 1024;     // <= 512 required by scanB

    char* p = (char*)d_ws;
    unsigned short* msgb = (unsigned short*)p; p += align256((size_t)N * Hh * sizeof(unsigned short));
    unsigned short* Yg = (unsigned short*)p;   p += align256((size_t)E * Hh * sizeof(unsigned short));
    int* srcS = (int*)p;                p += align256((size_t)E * sizeof(int));
    int* eidS = (int*)p;                p += align256((size_t)E * sizeof(int));
    int* yposS = (int*)p;               p += align256((size_t)E * sizeof(int));
    int* rowptrD = (int*)p;             p += align256(((size_t)4 * N + 1) * sizeof(int));
    int* cur = (int*)p;                 p += align256((size_t)nb * sizeof(int));   // counts -> cursors
    int* bsum = (int*)p;                p += align256(1024 * sizeof(int));
    unsigned short* h_bf = (unsigned short*)p; p += align256((size_t)N * Hh * sizeof(unsigned short));
    unsigned short* W1bf = (unsigned short*)p; p += align256((size_t)Tt * K1 * Hh * sizeof(unsigned short));
    unsigned short* W2bf = (unsigned short*)p; p += align256((size_t)Tt * Hh * Hh * sizeof(unsigned short));

    hipMemsetAsync(cur, 0, (size_t)nb * sizeof(int), stream);

    {
        int n4h = N * Hh / 4, n41 = Tt * K1 * Hh / 4, n42 = Tt * Hh * Hh / 4;
        cast_kernel<<<(n4h + 255) / 256, 256, 0, stream>>>(h, h_bf, n4h);
        cast_kernel<<<(n41 + 255) / 256, 256, 0, stream>>>(W1, W1bf, n41);
        cast_kernel<<<(n42 + 255) / 256, 256, 0, stream>>>(W2, W2bf, n42);
    }

    hist_kernel<<<1024, 256, 0, stream>>>(et, eidx, E, N, cur);
    scanA_kernel<<<sblocks, 256, 0, stream>>>(cur, nb, bsum);
    scanB_kernel<<<1, 512, 0, stream>>>(bsum, sblocks, rowptrD, 4 * N, E);
    scanC_kernel<<<sblocks, 256, 0, stream>>>(cur, nb, 4 * N, bsum, rowptrD);
    fill2_kernel<<<1024, 256, 0, stream>>>(et, eidx, E, N, cur, srcS, eidS, yposS);

    l1_kernel<<<1024, 512, 0, stream>>>(h_bf, srcS, eidS, yposS, eattr, W1bf, b1,
                                        rowptrD, Yg, N);
    zgemm_kernel<<<(N + 63) / 64, 256, 0, stream>>>(Yg, rowptrD, W2bf, b2, msgb, N);

    int gblocks = (N + 127) / 128;
    gru_kernel<<<gblocks, 512, 0, stream>>>(h, msgb, w_ih, w_hh, b_ih, b_hh, (float*)d_out, N);
}

// Round 8
// 489.066 us; speedup vs baseline: 12.4369x; 1.1677x over previous
//
#include <hip/hip_runtime.h>
#include <stdint.h>

#define Hh 128
#define Aa 16
#define Tt 4
#define K1 144
#define W1T_LD 168   // pad: stride 336B -> bank advance 20 dw -> 2-way (free)
#define WG_LD  136   // pad: stride 272B -> bank advance 4 dw  -> 2-way (free)
#define YT_LD  136   // epilogue tile row stride (u16): 16B-aligned rows, <=2-way banks

typedef float f32x4 __attribute__((ext_vector_type(4)));
typedef __bf16 bf16x8 __attribute__((ext_vector_type(8)));
typedef unsigned short u16x8 __attribute__((ext_vector_type(8)));
typedef unsigned short u16x4 __attribute__((ext_vector_type(4)));
typedef unsigned short u16x2 __attribute__((ext_vector_type(2)));

static __device__ __forceinline__ unsigned short f2bf(float f) {
    unsigned u = __builtin_bit_cast(unsigned, f);
    u += 0x7fffu + ((u >> 16) & 1u);   // RNE
    return (unsigned short)(u >> 16);
}

static __device__ __forceinline__ float bf2f(unsigned short u) {
    return __builtin_bit_cast(float, (unsigned)u << 16);
}

static __device__ __forceinline__ bf16x8 pack8(const float* __restrict__ x) {
    f32x4 a = *(const f32x4*)x;
    f32x4 b = *(const f32x4*)(x + 4);
    u16x8 t;
    t[0] = f2bf(a[0]); t[1] = f2bf(a[1]); t[2] = f2bf(a[2]); t[3] = f2bf(a[3]);
    t[4] = f2bf(b[0]); t[5] = f2bf(b[1]); t[6] = f2bf(b[2]); t[7] = f2bf(b[3]);
    return __builtin_bit_cast(bf16x8, t);
}

static __device__ __forceinline__ bf16x8 zero_bf8() {
    u16x8 z = {0, 0, 0, 0, 0, 0, 0, 0};
    return __builtin_bit_cast(bf16x8, z);
}

// ============ bf16 pre-cast
__global__ void cast_kernel(const float* __restrict__ src, unsigned short* __restrict__ dst, int n4) {
    int i = blockIdx.x * blockDim.x + threadIdx.x;
    if (i < n4) {
        f32x4 v = *(const f32x4*)(src + (size_t)i * 4);
        u16x4 o;
        o[0] = f2bf(v[0]); o[1] = f2bf(v[1]); o[2] = f2bf(v[2]); o[3] = f2bf(v[3]);
        *(u16x4*)(dst + (size_t)i * 4) = o;
    }
}

// ============ dual bucketing: bins [0,4N) by (type,dst), bins [4N,8N) by (type,src)
// hist counts AND captures per-edge in-bin rank (atomicAdd return), packed 16|16.
// (fill then needs ZERO atomics: pos = binstart + rank.)
__global__ void hist_kernel(const int* __restrict__ et, const int* __restrict__ eidx,
                            int E, int N, int* __restrict__ cnt, unsigned* __restrict__ rank) {
    for (int i = blockIdx.x * blockDim.x + threadIdx.x; i < E; i += gridDim.x * blockDim.x) {
        int tt = et[i];
        unsigned rD = (unsigned)atomicAdd(&cnt[tt * N + eidx[E + i]], 1);
        unsigned rS = (unsigned)atomicAdd(&cnt[4 * N + tt * N + eidx[i]], 1);
        rank[i] = rD | (rS << 16);   // bin occupancy << 65536 (Poisson-4 over 200K bins)
    }
}

// per-1024-chunk block sums
__global__ void scanA_kernel(const int* __restrict__ deg2, int nb, int* __restrict__ bsum) {
    __shared__ int red[256];
    const int t = threadIdx.x;
    const int i0 = blockIdx.x * 1024 + t * 4;
    int s = 0;
    #pragma unroll
    for (int j = 0; j < 4; j++) if (i0 + j < nb) s += deg2[i0 + j];
    red[t] = s; __syncthreads();
    for (int d = 128; d > 0; d >>= 1) {
        if (t < d) red[t] += red[t + d];
        __syncthreads();
    }
    if (t == 0) bsum[blockIdx.x] = red[0];
}

// single-block exclusive scan of block sums (nblocks <= 512); also closes dst rowptr
__global__ void scanB_kernel(int* __restrict__ bsum, int nblocks,
                             int* __restrict__ rowptrD, int fourN, int E) {
    __shared__ int ts[512];
    const int t = threadIdx.x;
    int v = (t < nblocks) ? bsum[t] : 0;
    ts[t] = v; __syncthreads();
    for (int d = 1; d < 512; d <<= 1) {
        int x = (t >= d) ? ts[t - d] : 0;
        __syncthreads();
        ts[t] += x;
        __syncthreads();
    }
    if (t < nblocks) bsum[t] = ts[t] - v;   // exclusive
    if (t == 0) rowptrD[fourN] = E;         // dst half always sums to E
}

// per-chunk exclusive scan + global offset; rowptrD for dst bins, bin starts in-place
__global__ void scanC_kernel(int* __restrict__ cur, int nb, int fourN,
                             const int* __restrict__ bsum, int* __restrict__ rowptrD) {
    __shared__ int ts[256];
    const int t = threadIdx.x;
    const int i0 = blockIdx.x * 1024 + t * 4;
    int v[4];
    #pragma unroll
    for (int j = 0; j < 4; j++) v[j] = (i0 + j < nb) ? cur[i0 + j] : 0;
    int s = v[0] + v[1] + v[2] + v[3];
    ts[t] = s; __syncthreads();
    for (int d = 1; d < 256; d <<= 1) {
        int x = (t >= d) ? ts[t - d] : 0;
        __syncthreads();
        ts[t] += x;
        __syncthreads();
    }
    int run = bsum[blockIdx.x] + ts[t] - s;
    #pragma unroll
    for (int j = 0; j < 4; j++) {
        if (i0 + j < nb) {
            if (i0 + j < fourN) rowptrD[i0 + j] = run;
            cur[i0 + j] = run;   // in-place: counts -> bin start offsets
            run += v[j];
        }
    }
}

// atomic-free placement: one packed int4 record per edge (single dirty line, was 3)
__global__ void fill2_kernel(const int* __restrict__ et, const int* __restrict__ eidx,
                             int E, int N, const int* __restrict__ binstart,
                             const unsigned* __restrict__ rank, int4* __restrict__ rec) {
    for (int i = blockIdx.x * blockDim.x + threadIdx.x; i < E; i += gridDim.x * blockDim.x) {
        int tt = et[i];
        int d = eidx[E + i], s = eidx[i];
        unsigned r = rank[i];
        int posD = binstart[tt * N + d] + (int)(r & 0xffffu);
        int posS = binstart[4 * N + tt * N + s] + (int)(r >> 16) - E;
        rec[posS] = make_int4(s, i, posD, 0);
    }
}

// ---------------- layer 1: iterate edges in (type,src) order -> sequential h gather;
// write Y rows to (type,dst) position via LDS-transposed full-line stores.
// BLOCK = 512 threads = 8 WAVES -> per-wave tile sized [8 waves][8 rows].
// LDS total: 43008 + 512 + 17408 = 60928 B (< 64 KB).
__global__ __launch_bounds__(512) void l1_kernel(
    const unsigned short* __restrict__ h_bf, const int4* __restrict__ rec,
    const float* __restrict__ eattr, const unsigned short* __restrict__ W1bf,
    const float* __restrict__ b1, const int* __restrict__ rowptrD,
    unsigned short* __restrict__ Yg, int N)
{
    __shared__ unsigned short W1T[128 * W1T_LD];
    __shared__ float b1s[128];
    __shared__ unsigned short yt[8 * 8 * YT_LD];   // 8 waves x 8 rows
    const int t = blockIdx.x & 3;
    const int lb = blockIdx.x >> 2;
    const int nbk = gridDim.x >> 2;
    const int tid = threadIdx.x;

    for (int idx = tid; idx < K1 * Hh; idx += 512) {
        int k = idx >> 7, n = idx & 127;
        W1T[n * W1T_LD + k] = W1bf[((size_t)t * K1 + k) * Hh + n];
    }
    for (int idx = tid; idx < (W1T_LD - K1) * Hh; idx += 512) {
        int k = K1 + (idx % (W1T_LD - K1)), n = idx / (W1T_LD - K1);
        W1T[n * W1T_LD + k] = 0;   // zero pad k=144..167 (read up to 159)
    }
    if (tid < 128) b1s[tid] = b1[t * Hh + tid];
    __syncthreads();

    // src-order segment of type t coincides positionally with dst-order boundaries
    const int tstart = rowptrD[t * N];
    const int tend = rowptrD[(t + 1) * N];
    const int cnt = tend - tstart;
    const int ntiles = (cnt + 255) >> 8;
    const int w = tid >> 6, lane = tid & 63;
    const int l15 = lane & 15, q = lane >> 4;
    unsigned short* __restrict__ ytw = yt + w * 8 * YT_LD;

    for (int tile = lb; tile < ntiles; tile += nbk) {
        const int p0 = tstart + tile * 256 + w * 32;
        const int pa = p0 + l15, pb = p0 + 16 + l15;
        const bool va = pa < tend, vb = pb < tend;
        const int4 ra = rec[va ? pa : tstart];
        const int4 rb = rec[vb ? pb : tstart];
        const int sa = ra.x, sb = rb.x;
        const int ea = ra.y, eb = rb.y;
        const int ypa = ra.z, ypb = rb.z;
        const unsigned short* __restrict__ hA = h_bf + (size_t)sa * Hh;
        const unsigned short* __restrict__ hB = h_bf + (size_t)sb * Hh;

        f32x4 acc[8][2];
        #pragma unroll
        for (int mt = 0; mt < 8; mt++) {
            acc[mt][0] = (f32x4){0.f, 0.f, 0.f, 0.f};
            acc[mt][1] = (f32x4){0.f, 0.f, 0.f, 0.f};
        }

        #pragma unroll
        for (int ks = 0; ks < 5; ks++) {
            const int k0 = ks * 32;
            bf16x8 fb_a, fb_b;
            if (ks < 4) {
                fb_a = __builtin_bit_cast(bf16x8, *(const u16x8*)(hA + k0 + q * 8));
                fb_b = __builtin_bit_cast(bf16x8, *(const u16x8*)(hB + k0 + q * 8));
            } else if (q < 2) {
                fb_a = pack8(eattr + (size_t)ea * Aa + q * 8);
                fb_b = pack8(eattr + (size_t)eb * Aa + q * 8);
            } else {
                fb_a = zero_bf8();
                fb_b = zero_bf8();
            }
            #pragma unroll
            for (int mt = 0; mt < 8; mt++) {
                bf16x8 fa = *(const bf16x8*)&W1T[(mt * 16 + l15) * W1T_LD + k0 + q * 8];
                acc[mt][0] = __builtin_amdgcn_mfma_f32_16x16x32_bf16(fa, fb_a, acc[mt][0], 0, 0, 0);
                acc[mt][1] = __builtin_amdgcn_mfma_f32_16x16x32_bf16(fa, fb_b, acc[mt][1], 0, 0, 0);
            }
        }

        // epilogue: 4 subpasses x 8 rows: bias+relu -> wave-private LDS tile ->
        // full-row 16B/lane stores to the edge's (type,dst) position.
        #pragma unroll
        for (int g = 0; g < 2; g++) {
            const int yp = g ? ypb : ypa;
            #pragma unroll
            for (int s = 0; s < 2; s++) {
                if ((l15 >> 3) == s) {
                    #pragma unroll
                    for (int mt = 0; mt < 8; mt++) {
                        f32x4 bias = *(const f32x4*)&b1s[mt * 16 + q * 4];
                        u16x4 y;
                        #pragma unroll
                        for (int i = 0; i < 4; i++) {
                            float v = acc[mt][g][i] + bias[i];
                            y[i] = f2bf(v > 0.f ? v : 0.f);
                        }
                        *(u16x4*)&ytw[(l15 & 7) * YT_LD + mt * 16 + q * 4] = y;
                    }
                }
                __asm__ volatile("s_waitcnt lgkmcnt(0)" ::: "memory");
                #pragma unroll
                for (int r0 = 0; r0 < 2; r0++) {
                    const int el = r0 * 4 + q;   // 0..7 within this 8-row subpass
                    if (p0 + g * 16 + s * 8 + el < tend) {
                        const int yrow = __shfl(yp, s * 8 + el);  // lane holds its edge's dst pos
                        u16x8 v = *(const u16x8*)&ytw[el * YT_LD + l15 * 8];
                        *(u16x8*)&Yg[(size_t)yrow * Hh + l15 * 8] = v;
                    }
                }
                __asm__ volatile("s_waitcnt lgkmcnt(0)" ::: "memory");
            }
        }
    }
}

// ---------------- fused segment-sum + second GEMM:
// msg[n] = sum_t (sum_{e in (t,n)-segment} Y[e]) @ W2[t] + cnt[n,t]*b2[t]   (bf16 out)
__global__ __launch_bounds__(256) void zgemm_kernel(
    const unsigned short* __restrict__ Yg, const int* __restrict__ rowptrD,
    const unsigned short* __restrict__ W2bf, const float* __restrict__ b2,
    unsigned short* __restrict__ msgb, int N)
{
    __shared__ unsigned short W2T[128 * WG_LD];
    __shared__ float b2s[512];
    __shared__ int cntS[4 * 64];   // [wave][t*16 + l15]
    const int tid = threadIdx.x;
    const int w = tid >> 6, lane = tid & 63;
    const int l15 = lane & 15, q = lane >> 4;
    const int nodebase = blockIdx.x * 64 + w * 16;
    const int nA = min(nodebase + l15, N - 1);

    if (tid < 512) {
        b2s[tid] = b2[tid];
        b2s[tid + 256] = b2[tid + 256];
    }

    f32x4 acc[8];
    #pragma unroll
    for (int ct = 0; ct < 8; ct++) acc[ct] = (f32x4){0.f, 0.f, 0.f, 0.f};

    for (int t = 0; t < Tt; t++) {
        __syncthreads();
        for (int idx = tid; idx < Hh * Hh; idx += 256) {
            int k = idx >> 7, n = idx & 127;
            W2T[n * WG_LD + k] = W2bf[((size_t)t * Hh + k) * Hh + n];
        }
        __syncthreads();

        const int seg = rowptrD[(size_t)t * N + nA];
        const int len = rowptrD[(size_t)t * N + nA + 1] - seg;
        cntS[w * 64 + t * 16 + l15] = len;

        float asum[32];
        #pragma unroll
        for (int i = 0; i < 32; i++) asum[i] = 0.f;
        for (int j = 0; j < len; j++) {
            const unsigned short* __restrict__ yr = Yg + (size_t)(seg + j) * Hh;
            #pragma unroll
            for (int ks = 0; ks < 4; ks++) {
                u16x8 yv = *(const u16x8*)(yr + ks * 32 + q * 8);
                #pragma unroll
                for (int e = 0; e < 8; e++) asum[ks * 8 + e] += bf2f(yv[e]);
            }
        }

        #pragma unroll
        for (int ks = 0; ks < 4; ks++) {
            u16x8 fr;
            #pragma unroll
            for (int e = 0; e < 8; e++) fr[e] = f2bf(asum[ks * 8 + e]);
            bf16x8 fa = __builtin_bit_cast(bf16x8, fr);
            #pragma unroll
            for (int ct = 0; ct < 8; ct++) {
                bf16x8 fb = *(const bf16x8*)&W2T[(ct * 16 + l15) * WG_LD + ks * 32 + q * 8];
                acc[ct] = __builtin_amdgcn_mfma_f32_16x16x32_bf16(fa, fb, acc[ct], 0, 0, 0);
            }
        }
    }
    __syncthreads();   // drain LDS writes (cntS) before epilogue reads

    #pragma unroll
    for (int ct = 0; ct < 8; ct++) {
        const int c = ct * 16 + l15;
        #pragma unroll
        for (int i = 0; i < 4; i++) {
            int node = nodebase + q * 4 + i;
            if (node < N) {
                float bias = 0.f;
                #pragma unroll
                for (int t = 0; t < Tt; t++)
                    bias += (float)cntS[w * 64 + t * 16 + q * 4 + i] * b2s[t * 128 + c];
                msgb[(size_t)node * Hh + c] = f2bf(acc[ct][i] + bias);
            }
        }
    }
}

// ---------------- GRU: out = (1-z)*n + z*h, gate-by-gate bf16 LDS weight staging
__global__ __launch_bounds__(512) void gru_kernel(
    const float* __restrict__ h, const unsigned short* __restrict__ msgb,
    const unsigned short* __restrict__ wihb, const unsigned short* __restrict__ whhb,
    const float* __restrict__ b_ih, const float* __restrict__ b_hh,
    float* __restrict__ out, int N)
{
    __shared__ unsigned short Wg[128 * WG_LD];
    const int tid = threadIdx.x;
    const int w = tid >> 6, lane = tid & 63;
    const int l15 = lane & 15, q = lane >> 4;
    const int nodebase = blockIdx.x * 128 + w * 16;
    const int nA = min(nodebase + l15, N - 1);
    const unsigned short* __restrict__ mrow = msgb + (size_t)nA * Hh;
    const float* __restrict__ hrow = h + (size_t)nA * Hh;

    f32x4 gr[8], gz[8], gin[8], ghn[8];
    #pragma unroll
    for (int ct = 0; ct < 8; ct++) {
        gr[ct] = (f32x4){0.f, 0.f, 0.f, 0.f};
        gz[ct] = (f32x4){0.f, 0.f, 0.f, 0.f};
        gin[ct] = (f32x4){0.f, 0.f, 0.f, 0.f};
        ghn[ct] = (f32x4){0.f, 0.f, 0.f, 0.f};
    }

    auto stage = [&](const unsigned short* __restrict__ Ws, int gate) {
        __syncthreads();
        for (int idx = tid; idx < Hh * Hh / 2; idx += 512) {
            int o = idx >> 6, kk = (idx & 63) * 2;
            *(u16x2*)&Wg[o * WG_LD + kk] =
                *(const u16x2*)&Ws[(size_t)gate * Hh * Hh + o * Hh + kk];
        }
        __syncthreads();
    };
    auto matmulM = [&](f32x4* acc) {   // A rows from bf16 msg
        #pragma unroll
        for (int ks = 0; ks < 4; ks++) {
            bf16x8 fa = __builtin_bit_cast(bf16x8, *(const u16x8*)(mrow + ks * 32 + q * 8));
            #pragma unroll
            for (int ct = 0; ct < 8; ct++) {
                bf16x8 fb = *(const bf16x8*)&Wg[(ct * 16 + l15) * WG_LD + ks * 32 + q * 8];
                acc[ct] = __builtin_amdgcn_mfma_f32_16x16x32_bf16(fa, fb, acc[ct], 0, 0, 0);
            }
        }
    };
    auto matmulH = [&](f32x4* acc) {   // A rows from fp32 h
        #pragma unroll
        for (int ks = 0; ks < 4; ks++) {
            bf16x8 fa = pack8(hrow + ks * 32 + q * 8);
            #pragma unroll
            for (int ct = 0; ct < 8; ct++) {
                bf16x8 fb = *(const bf16x8*)&Wg[(ct * 16 + l15) * WG_LD + ks * 32 + q * 8];
                acc[ct] = __builtin_amdgcn_mfma_f32_16x16x32_bf16(fa, fb, acc[ct], 0, 0, 0);
            }
        }
    };

    stage(wihb, 0); matmulM(gr);
    stage(whhb, 0); matmulH(gr);
    stage(wihb, 1); matmulM(gz);
    stage(whhb, 1); matmulH(gz);
    stage(wihb, 2); matmulM(gin);
    stage(whhb, 2); matmulH(ghn);

    #pragma unroll
    for (int ct = 0; ct < 8; ct++) {
        int c = ct * 16 + l15;
        float bir = b_ih[c],       bhr = b_hh[c];
        float biz = b_ih[128 + c], bhz = b_hh[128 + c];
        float bin = b_ih[256 + c], bhn = b_hh[256 + c];
        #pragma unroll
        for (int i = 0; i < 4; i++) {
            int node = nodebase + q * 4 + i;
            if (node < N) {
                float rv = 1.f / (1.f + __expf(-(gr[ct][i] + bir + bhr)));
                float zv = 1.f / (1.f + __expf(-(gz[ct][i] + biz + bhz)));
                float npre = gin[ct][i] + bin + rv * (ghn[ct][i] + bhn);
                float e2 = __expf(-2.f * npre);
                float nv = (1.f - e2) / (1.f + e2);
                float hv = h[(size_t)node * Hh + c];
                out[(size_t)node * Hh + c] = (1.f - zv) * nv + zv * hv;
            }
        }
    }
}

static inline size_t align256(size_t x) { return (x + 255) & ~(size_t)255; }

extern "C" void kernel_launch(void* const* d_in, const int* in_sizes, int n_in,
                              void* d_out, int out_size, void* d_ws, size_t ws_size,
                              hipStream_t stream)
{
    const float* h     = (const float*)d_in[0];
    const int*   eidx  = (const int*)d_in[1];
    const int*   et    = (const int*)d_in[2];
    const float* eattr = (const float*)d_in[3];
    const float* W1    = (const float*)d_in[4];
    const float* b1    = (const float*)d_in[5];
    const float* W2    = (const float*)d_in[6];
    const float* b2    = (const float*)d_in[7];
    const float* w_ih  = (const float*)d_in[8];
    const float* w_hh  = (const float*)d_in[9];
    const float* b_ih  = (const float*)d_in[10];
    const float* b_hh  = (const float*)d_in[11];

    const int N = in_sizes[0] / Hh;
    const int E = in_sizes[1] / 2;
    const int nb = 8 * N;                       // [0,4N)=(type,dst), [4N,8N)=(type,src)
    const int sblocks = (nb + 1023) / 1024;     // <= 512 required by scanB

    char* p = (char*)d_ws;
    unsigned short* msgb = (unsigned short*)p; p += align256((size_t)N * Hh * sizeof(unsigned short));
    unsigned short* Yg = (unsigned short*)p;   p += align256((size_t)E * Hh * sizeof(unsigned short));
    int4* rec = (int4*)p;               p += align256((size_t)E * sizeof(int4));
    unsigned* rank = (unsigned*)p;      p += align256((size_t)E * sizeof(unsigned));
    int* rowptrD = (int*)p;             p += align256(((size_t)4 * N + 1) * sizeof(int));
    int* cur = (int*)p;                 p += align256((size_t)nb * sizeof(int));   // counts -> bin starts
    int* bsum = (int*)p;                p += align256(1024 * sizeof(int));
    unsigned short* h_bf = (unsigned short*)p; p += align256((size_t)N * Hh * sizeof(unsigned short));
    unsigned short* W1bf = (unsigned short*)p; p += align256((size_t)Tt * K1 * Hh * sizeof(unsigned short));
    unsigned short* W2bf = (unsigned short*)p; p += align256((size_t)Tt * Hh * Hh * sizeof(unsigned short));
    unsigned short* wihb = (unsigned short*)p; p += align256((size_t)3 * Hh * Hh * sizeof(unsigned short));
    unsigned short* whhb = (unsigned short*)p; p += align256((size_t)3 * Hh * Hh * sizeof(unsigned short));

    hipMemsetAsync(cur, 0, (size_t)nb * sizeof(int), stream);

    {
        int n4h = N * Hh / 4, n41 = Tt * K1 * Hh / 4, n42 = Tt * Hh * Hh / 4;
        int n4g = 3 * Hh * Hh / 4;
        cast_kernel<<<(n4h + 255) / 256, 256, 0, stream>>>(h, h_bf, n4h);
        cast_kernel<<<(n41 + 255) / 256, 256, 0, stream>>>(W1, W1bf, n41);
        cast_kernel<<<(n42 + 255) / 256, 256, 0, stream>>>(W2, W2bf, n42);
        cast_kernel<<<(n4g + 255) / 256, 256, 0, stream>>>(w_ih, wihb, n4g);
        cast_kernel<<<(n4g + 255) / 256, 256, 0, stream>>>(w_hh, whhb, n4g);
    }

    hist_kernel<<<1024, 256, 0, stream>>>(et, eidx, E, N, cur, rank);
    scanA_kernel<<<sblocks, 256, 0, stream>>>(cur, nb, bsum);
    scanB_kernel<<<1, 512, 0, stream>>>(bsum, sblocks, rowptrD, 4 * N, E);
    scanC_kernel<<<sblocks, 256, 0, stream>>>(cur, nb, 4 * N, bsum, rowptrD);
    fill2_kernel<<<1024, 256, 0, stream>>>(et, eidx, E, N, cur, rank, rec);

    l1_kernel<<<1024, 512, 0, stream>>>(h_bf, rec, eattr, W1bf, b1, rowptrD, Yg, N);
    zgemm_kernel<<<(N + 63) / 64, 256, 0, stream>>>(Yg, rowptrD, W2bf, b2, msgb, N);

    int gblocks = (N + 127) / 128;
    gru_kernel<<<gblocks, 512, 0, stream>>>(h, msgb, wihb, whhb, b_ih, b_hh, (float*)d_out, N);
}